// Round 1
// baseline (1213.267 us; speedup 1.0000x reference)
//
#include <hip/hip_runtime.h>
#include <hip/hip_bf16.h>
#include <math.h>

#define B_ 2
#define S_ 2048
#define D_ 2048
#define NH_ 16
#define NKV_ 4
#define HD_ 128
#define REP_ 4
#define EPS_ 1e-6f
#define SCALE_ 0.08838834764831845f  // 1/sqrt(128)

typedef float f32x4 __attribute__((ext_vector_type(4)));
typedef short bf16x8 __attribute__((ext_vector_type(8)));
typedef short short4v __attribute__((ext_vector_type(4)));
typedef float float4v __attribute__((ext_vector_type(4)));

static __device__ __forceinline__ short f2bf(float f) {
    union { float f; unsigned u; } x{f};
    unsigned r = (x.u + 0x7fff + ((x.u >> 16) & 1)) >> 16;   // RTNE
    return (short)r;
}

// ---------------------------------------------------------------------------
// GEMM: C[M][N] = A[M][K] @ B[K][N].  A is fp32 or bf16(short), B fp32, C fp32.
// Block: 256 thr (4 waves, 2x2), tile 128x128, BK=32, mfma_f32_16x16x32_bf16.
// ---------------------------------------------------------------------------
template<typename TA>
__global__ __launch_bounds__(256) void gemm_kernel(const TA* __restrict__ A,
                                                   const float* __restrict__ Bm,
                                                   float* __restrict__ C,
                                                   int M, int N, int K) {
    constexpr int LDT = 40;  // 32 + 8 pad (keeps 16B alignment: 80B rows)
    __shared__ short As[128 * LDT];
    __shared__ short Bs[128 * LDT];   // stored transposed: Bs[n][k]

    const int tid  = threadIdx.x;
    const int bn   = blockIdx.x, bm = blockIdx.y;
    const int wave = tid >> 6, lane = tid & 63;
    const int quad = lane >> 4, l16 = lane & 15;
    const int wr = wave >> 1, wc = wave & 1;

    f32x4 acc[4][4];
    for (int i = 0; i < 4; ++i)
        for (int j = 0; j < 4; ++j) acc[i][j] = (f32x4){0.f, 0.f, 0.f, 0.f};

    for (int k0 = 0; k0 < K; k0 += 32) {
        __syncthreads();
        // stage A tile: 128 rows x 32 k
        for (int e = 0; e < 4; ++e) {
            int f   = tid + 256 * e;      // 0..1023
            int row = f >> 3;
            int kk  = (f & 7) << 2;
            const TA* src = A + (size_t)(bm * 128 + row) * K + k0 + kk;
            short4v o4;
            if constexpr (__is_same(TA, float)) {
                float4v v = *(const float4v*)src;
                o4.x = f2bf(v.x); o4.y = f2bf(v.y); o4.z = f2bf(v.z); o4.w = f2bf(v.w);
            } else {
                o4 = *(const short4v*)src;
            }
            *(short4v*)&As[row * LDT + kk] = o4;
        }
        // stage B tile transposed: 32 k x 128 n  ->  Bs[n][k]
        for (int e = 0; e < 4; ++e) {
            int f  = tid + 256 * e;
            int k  = f >> 5;
            int n4 = (f & 31) << 2;
            const float* src = Bm + (size_t)(k0 + k) * N + bn * 128 + n4;
            float4v v = *(const float4v*)src;
            Bs[(n4 + 0) * LDT + k] = f2bf(v.x);
            Bs[(n4 + 1) * LDT + k] = f2bf(v.y);
            Bs[(n4 + 2) * LDT + k] = f2bf(v.z);
            Bs[(n4 + 3) * LDT + k] = f2bf(v.w);
        }
        __syncthreads();

        bf16x8 af[4], bfv[4];
        for (int mt = 0; mt < 4; ++mt)
            af[mt] = *(const bf16x8*)&As[(wr * 64 + mt * 16 + l16) * LDT + quad * 8];
        for (int nt = 0; nt < 4; ++nt)
            bfv[nt] = *(const bf16x8*)&Bs[(wc * 64 + nt * 16 + l16) * LDT + quad * 8];
        for (int mt = 0; mt < 4; ++mt)
            for (int nt = 0; nt < 4; ++nt)
                acc[mt][nt] = __builtin_amdgcn_mfma_f32_16x16x32_bf16(
                    af[mt], bfv[nt], acc[mt][nt], 0, 0, 0);
    }

    for (int mt = 0; mt < 4; ++mt)
        for (int nt = 0; nt < 4; ++nt)
            for (int j = 0; j < 4; ++j) {
                int row = bm * 128 + wr * 64 + mt * 16 + quad * 4 + j;
                int col = bn * 128 + wc * 64 + nt * 16 + l16;
                C[(size_t)row * N + col] = acc[mt][nt][j];
            }
}

// ---------------------------------------------------------------------------
// RMSNorm + RoPE. One wave per (token, head) row of HD=128. Writes bf16.
// ---------------------------------------------------------------------------
__global__ __launch_bounds__(64) void rope_rms_kernel(const float* __restrict__ in,
                                                      const float* __restrict__ cosb,
                                                      const float* __restrict__ sinb,
                                                      const float* __restrict__ w,
                                                      short* __restrict__ out,
                                                      int nheads) {
    const int r    = blockIdx.x;          // token*nheads + head
    const int lane = threadIdx.x;         // 0..63
    const int spos = (r / nheads) % S_;
    const float* row = in + (size_t)r * HD_;
    float h1 = row[lane], h2 = row[lane + 64];
    float ss = h1 * h1 + h2 * h2;
    for (int off = 1; off < 64; off <<= 1) ss += __shfl_xor(ss, off);
    float rstd = rsqrtf(ss * (1.0f / HD_) + EPS_);
    float n1 = h1 * rstd * w[lane];
    float n2 = h2 * rstd * w[lane + 64];
    float c  = cosb[spos * HD_ + lane];
    float sn = sinb[spos * HD_ + lane];   // halves are duplicated in emb
    out[(size_t)r * HD_ + lane]      = f2bf(n1 * c - n2 * sn);
    out[(size_t)r * HD_ + lane + 64] = f2bf(n2 * c + n1 * sn);
}

// ---------------------------------------------------------------------------
// V: fp32 (b,s,g,d) -> bf16 transposed (b,g,d,s) so PV B-frags are contiguous.
// ---------------------------------------------------------------------------
__global__ __launch_bounds__(256) void vtrans_kernel(const float* __restrict__ vbuf,
                                                     short* __restrict__ vt) {
    size_t idx = (size_t)blockIdx.x * 256 + threadIdx.x;  // over B*NKV*HD*S
    int s  = idx & (S_ - 1);
    size_t r = idx >> 11;         // /S_
    int d  = r & (HD_ - 1);
    size_t r2 = r >> 7;           // /HD_
    int g  = r2 & (NKV_ - 1);
    int b  = (int)(r2 >> 2);
    float v = vbuf[(((size_t)(b * S_ + s)) * NKV_ + g) * HD_ + d];
    vt[idx] = f2bf(v);
}

// ---------------------------------------------------------------------------
// Flash-style causal GQA attention.
// Grid: (S/64, NH, B). Block 256 = 4 waves, each wave owns 16 Q rows.
// q/k bf16 token-major, v bf16 (b,g,d,s). Output bf16 (token, h*HD+d).
// ---------------------------------------------------------------------------
__global__ __launch_bounds__(256) void attn_kernel(const short* __restrict__ qr,
                                                   const short* __restrict__ kr,
                                                   const short* __restrict__ vt,
                                                   short* __restrict__ aout) {
    constexpr int LP = 72;  // 64 + 8 pad (144B rows, 16B aligned)
    __shared__ short Pbuf[4 * 16 * LP];

    const int qt = blockIdx.x, h = blockIdx.y, b = blockIdx.z;
    const int wave = threadIdx.x >> 6, lane = threadIdx.x & 63;
    const int quad = lane >> 4, l16 = lane & 15;
    const int g  = h >> 2;            // REP = 4
    const int q0 = qt * 64 + wave * 16;

    // Q fragments (A-layout), kept for the whole kernel
    bf16x8 qf[4];
    {
        const short* qrow = qr + ((size_t)(b * S_ + q0 + l16) * NH_ + h) * HD_;
        for (int ks = 0; ks < 4; ++ks)
            qf[ks] = *(const bf16x8*)(qrow + ks * 32 + quad * 8);
    }

    f32x4 o[8];
    for (int i = 0; i < 8; ++i) o[i] = (f32x4){0.f, 0.f, 0.f, 0.f};
    float m_i[4] = {-INFINITY, -INFINITY, -INFINITY, -INFINITY};
    float l_i[4] = {0.f, 0.f, 0.f, 0.f};

    const short* vb = vt + ((size_t)(b * NKV_ + g) * HD_) * S_;
    short* pw = Pbuf + wave * 16 * LP;

    for (int kt = 0; kt <= qt; ++kt) {
        // ---- S = Q K^T * scale ----
        float st[4][4];
        for (int nt = 0; nt < 4; ++nt) {
            f32x4 acc = (f32x4){0.f, 0.f, 0.f, 0.f};
            int key = kt * 64 + nt * 16 + l16;
            const short* krow = kr + ((size_t)((b * S_ + key) * NKV_ + g)) * HD_;
            for (int ks = 0; ks < 4; ++ks)
                acc = __builtin_amdgcn_mfma_f32_16x16x32_bf16(
                    qf[ks], *(const bf16x8*)(krow + ks * 32 + quad * 8), acc, 0, 0, 0);
            for (int j = 0; j < 4; ++j) st[nt][j] = acc[j] * SCALE_;
        }
        // causal mask (only diagonal tile needs it)
        if (kt == qt) {
            int rloc = wave * 16 + quad * 4;
            for (int nt = 0; nt < 4; ++nt) {
                int cloc = nt * 16 + l16;
                for (int j = 0; j < 4; ++j)
                    if (cloc > rloc + j) st[nt][j] = -INFINITY;
            }
        }
        // ---- online softmax ----
        float alpha[4];
        for (int j = 0; j < 4; ++j) {
            float m = fmaxf(fmaxf(st[0][j], st[1][j]), fmaxf(st[2][j], st[3][j]));
            m = fmaxf(m, m_i[j]);
            for (int off = 1; off < 16; off <<= 1) m = fmaxf(m, __shfl_xor(m, off));
            alpha[j] = __expf(m_i[j] - m);
            m_i[j] = m;
            float rs = 0.f;
            for (int nt = 0; nt < 4; ++nt) {
                float p = __expf(st[nt][j] - m);
                st[nt][j] = p;
                rs += p;
            }
            for (int off = 1; off < 16; off <<= 1) rs += __shfl_xor(rs, off);
            l_i[j] = alpha[j] * l_i[j] + rs;
        }
        for (int d8 = 0; d8 < 8; ++d8)
            for (int j = 0; j < 4; ++j) o[d8][j] *= alpha[j];
        // ---- P: C-layout -> LDS -> A-layout ----
        for (int nt = 0; nt < 4; ++nt)
            for (int j = 0; j < 4; ++j)
                pw[(quad * 4 + j) * LP + nt * 16 + l16] = f2bf(st[nt][j]);
        // ---- O += P V ----
        for (int ks2 = 0; ks2 < 2; ++ks2) {
            bf16x8 pf = *(const bf16x8*)(pw + l16 * LP + ks2 * 32 + quad * 8);
            for (int d8 = 0; d8 < 8; ++d8) {
                const short* vrow = vb + (size_t)(d8 * 16 + l16) * S_
                                  + kt * 64 + ks2 * 32 + quad * 8;
                o[d8] = __builtin_amdgcn_mfma_f32_16x16x32_bf16(
                    pf, *(const bf16x8*)vrow, o[d8], 0, 0, 0);
            }
        }
    }
    // ---- normalize + store bf16 (token, h*HD+d) ----
    float inv_l[4];
    for (int j = 0; j < 4; ++j) inv_l[j] = 1.0f / l_i[j];
    for (int d8 = 0; d8 < 8; ++d8)
        for (int j = 0; j < 4; ++j) {
            size_t tok = (size_t)(b * S_ + q0 + quad * 4 + j);
            aout[(tok * NH_ + h) * HD_ + d8 * 16 + l16] = f2bf(o[d8][j] * inv_l[j]);
        }
}

// ---------------------------------------------------------------------------
extern "C" void kernel_launch(void* const* d_in, const int* in_sizes, int n_in,
                              void* d_out, int out_size, void* d_ws, size_t ws_size,
                              hipStream_t stream) {
    (void)in_sizes; (void)n_in; (void)out_size; (void)ws_size;
    const float* x    = (const float*)d_in[0];
    const float* cosb = (const float*)d_in[1];
    const float* sinb = (const float*)d_in[2];
    const float* Wq   = (const float*)d_in[3];
    const float* Wk   = (const float*)d_in[4];
    const float* Wv   = (const float*)d_in[5];
    const float* Wo   = (const float*)d_in[6];
    const float* qw   = (const float*)d_in[7];
    const float* kw   = (const float*)d_in[8];
    float* out = (float*)d_out;

    char* ws = (char*)d_ws;
    float* qbuf   = (float*)ws;                 ws += (size_t)4096 * 2048 * 4;  // 32MB
    float* kbuf   = (float*)ws;                 ws += (size_t)4096 * 512 * 4;   // 8MB
    float* vbuf   = (float*)ws;                 ws += (size_t)4096 * 512 * 4;   // 8MB
    short* q_rope = (short*)ws;                 ws += (size_t)4096 * 2048 * 2;  // 16MB
    short* k_rope = (short*)ws;                 ws += (size_t)4096 * 512 * 2;   // 4MB
    short* vt     = (short*)ws;                 ws += (size_t)4096 * 512 * 2;   // 4MB
    short* a_out  = (short*)ws;                 ws += (size_t)4096 * 2048 * 2;  // 16MB

    const int M = B_ * S_;  // 4096

    // QKV projections
    gemm_kernel<float><<<dim3(NH_ * HD_ / 128, M / 128), 256, 0, stream>>>(
        x, Wq, qbuf, M, NH_ * HD_, D_);
    gemm_kernel<float><<<dim3(NKV_ * HD_ / 128, M / 128), 256, 0, stream>>>(
        x, Wk, kbuf, M, NKV_ * HD_, D_);
    gemm_kernel<float><<<dim3(NKV_ * HD_ / 128, M / 128), 256, 0, stream>>>(
        x, Wv, vbuf, M, NKV_ * HD_, D_);

    // RMSNorm + RoPE (q, k); V transpose+cast
    rope_rms_kernel<<<M * NH_, 64, 0, stream>>>(qbuf, cosb, sinb, qw, q_rope, NH_);
    rope_rms_kernel<<<M * NKV_, 64, 0, stream>>>(kbuf, cosb, sinb, kw, k_rope, NKV_);
    vtrans_kernel<<<(B_ * NKV_ * HD_ * S_) / 256, 256, 0, stream>>>(vbuf, vt);

    // Causal GQA flash attention
    attn_kernel<<<dim3(S_ / 64, NH_, B_), 256, 0, stream>>>(q_rope, k_rope, vt, a_out);

    // Output projection
    gemm_kernel<short><<<dim3(D_ / 128, M / 128), 256, 0, stream>>>(
        a_out, Wo, out, M, D_, NH_ * HD_);
}

// Round 3
// 443.765 us; speedup vs baseline: 2.7340x; 2.7340x over previous
//
#include <hip/hip_runtime.h>
#include <hip/hip_bf16.h>
#include <math.h>

#define B_ 2
#define S_ 2048
#define D_ 2048
#define NH_ 16
#define NKV_ 4
#define HD_ 128
#define EPS_ 1e-6f
#define SCALE_ 0.08838834764831845f  // 1/sqrt(128)
#define NQKV_ 3072                   // fused QKV output width
#define KOFF_ 2048                   // k slice column offset in fused qkv
#define VOFF_ 2560                   // v slice column offset in fused qkv

typedef float f32x4 __attribute__((ext_vector_type(4)));
typedef short bf16x8 __attribute__((ext_vector_type(8)));
typedef short short4v __attribute__((ext_vector_type(4)));
typedef float float4v __attribute__((ext_vector_type(4)));

static __device__ __forceinline__ short f2bf(float f) {
    union { float f; unsigned u; } x{f};
    unsigned r = (x.u + 0x7fff + ((x.u >> 16) & 1)) >> 16;   // RTNE
    return (short)r;
}
static __device__ __forceinline__ float bf2f(short s) {
    union { unsigned u; float f; } x; x.u = ((unsigned)(unsigned short)s) << 16; return x.f;
}

#define AS1(p) ((const __attribute__((address_space(1))) void*)(p))
#define AS3(p) ((__attribute__((address_space(3))) void*)(p))
static __device__ __forceinline__ void async16(const void* g, void* l) {
    __builtin_amdgcn_global_load_lds(AS1(g), AS3(l), 16, 0, 0);
}

// ---------------------------------------------------------------------------
// fp32 -> bf16 flat cast (for x). 4 elems/thread.
// ---------------------------------------------------------------------------
__global__ __launch_bounds__(256) void cast_kernel(const float* __restrict__ in,
                                                   short* __restrict__ out) {
    size_t i = ((size_t)blockIdx.x * 256 + threadIdx.x) * 4;
    float4v v = *(const float4v*)(in + i);
    short4v o; o.x = f2bf(v.x); o.y = f2bf(v.y); o.z = f2bf(v.z); o.w = f2bf(v.w);
    *(short4v*)(out + i) = o;
}

// ---------------------------------------------------------------------------
// fp32 [K][N] -> bf16 [N][K] transpose+cast. 64x64 tiles, 256 threads.
// ---------------------------------------------------------------------------
__global__ __launch_bounds__(256) void transpose_cast_kernel(const float* __restrict__ in,
                                                             short* __restrict__ out,
                                                             int K, int N) {
    __shared__ float tile[64][65];
    const int n0 = blockIdx.x * 64, k0 = blockIdx.y * 64;
    const int tid = threadIdx.x;
    for (int r = 0; r < 16; ++r) {
        int k = r * 4 + (tid >> 6);
        int n = tid & 63;
        tile[k][n] = in[(size_t)(k0 + k) * N + n0 + n];
    }
    __syncthreads();
    for (int r = 0; r < 16; ++r) {
        int n = r * 4 + (tid >> 6);
        int k = tid & 63;
        out[(size_t)(n0 + n) * K + k0 + k] = f2bf(tile[k][n]);
    }
}

// ---------------------------------------------------------------------------
// m97-style GEMM: C[M][N] = A[M][K] @ Bt[N][K]^T, A/Bt bf16, C fp32 or bf16.
// 128x128 tile, BK=32, global_load_lds width-16, rotation-swizzled LDS chunks.
// ---------------------------------------------------------------------------
template<typename TC>
__global__ __launch_bounds__(256) void gemm_tt_kernel(const short* __restrict__ A,
                                                      const short* __restrict__ Bt,
                                                      TC* __restrict__ C,
                                                      int M, int N, int K) {
    __shared__ short As[128 * 32];   // [row][4 chunks of 8 bf16], chunk c at slot (c + (r>>1))&3
    __shared__ short Bs[128 * 32];

    const int tid  = threadIdx.x;
    const int bn   = blockIdx.x, bm = blockIdx.y;
    const int wave = tid >> 6, lane = tid & 63;
    const int quad = lane >> 4, l16 = lane & 15;
    const int wr = wave >> 1, wc = wave & 1;

    f32x4 acc[4][4];
    for (int i = 0; i < 4; ++i)
        for (int j = 0; j < 4; ++j) acc[i][j] = (f32x4){0.f, 0.f, 0.f, 0.f};

    const short* Abase = A  + (size_t)(bm * 128) * K;
    const short* Bbase = Bt + (size_t)(bn * 128) * K;

    int ci0 = wave * 128 + lane;
    for (int k0 = 0; k0 < K; k0 += 32) {
        __syncthreads();
        for (int t = 0; t < 2; ++t) {
            int ci = ci0 + t * 64;          // 0..511
            int r  = ci >> 2;
            int c  = ((ci & 3) - (r >> 1)) & 3;
            size_t goff = (size_t)r * K + k0 + c * 8;
            async16(Abase + goff, &As[ci * 8]);
            async16(Bbase + goff, &Bs[ci * 8]);
        }
        __syncthreads();

        bf16x8 af[4], bfv[4];
        for (int mt = 0; mt < 4; ++mt) {
            int r = wr * 64 + mt * 16 + l16;
            af[mt] = *(const bf16x8*)&As[r * 32 + (((quad + (r >> 1)) & 3) * 8)];
        }
        for (int nt = 0; nt < 4; ++nt) {
            int r = wc * 64 + nt * 16 + l16;
            bfv[nt] = *(const bf16x8*)&Bs[r * 32 + (((quad + (r >> 1)) & 3) * 8)];
        }
        for (int mt = 0; mt < 4; ++mt)
            for (int nt = 0; nt < 4; ++nt)
                acc[mt][nt] = __builtin_amdgcn_mfma_f32_16x16x32_bf16(
                    af[mt], bfv[nt], acc[mt][nt], 0, 0, 0);
    }

    for (int mt = 0; mt < 4; ++mt)
        for (int nt = 0; nt < 4; ++nt)
            for (int j = 0; j < 4; ++j) {
                int row = bm * 128 + wr * 64 + mt * 16 + quad * 4 + j;
                int col = bn * 128 + wc * 64 + nt * 16 + l16;
                float v = acc[mt][nt][j];
                if constexpr (__is_same(TC, short))
                    C[(size_t)row * N + col] = f2bf(v);
                else
                    C[(size_t)row * N + col] = v;
            }
}

// ---------------------------------------------------------------------------
// RMSNorm + RoPE from bf16 qkv rows. 4 rows per 256-block (1/wave).
// HEAD_MAJOR=false: out (b,s,head,hd); true: out (b,head,s,hd).
// ---------------------------------------------------------------------------
template<int NHEADS, bool HEAD_MAJOR>
__global__ __launch_bounds__(256) void rope_rms_kernel(const short* __restrict__ qkv,
                                                       int coloff,
                                                       const float* __restrict__ cosb,
                                                       const float* __restrict__ sinb,
                                                       const float* __restrict__ w,
                                                       short* __restrict__ out) {
    const int r    = blockIdx.x * 4 + (threadIdx.x >> 6);  // token*NHEADS + head
    const int lane = threadIdx.x & 63;
    const int tok  = r / NHEADS, head = r % NHEADS;
    const int spos = tok & (S_ - 1);
    const short* row = qkv + (size_t)tok * NQKV_ + coloff + head * HD_;
    float h1 = bf2f(row[lane]), h2 = bf2f(row[lane + 64]);
    float ss = h1 * h1 + h2 * h2;
    for (int off = 1; off < 64; off <<= 1) ss += __shfl_xor(ss, off);
    float rstd = rsqrtf(ss * (1.0f / HD_) + EPS_);
    float n1 = h1 * rstd * w[lane];
    float n2 = h2 * rstd * w[lane + 64];
    float c  = cosb[spos * HD_ + lane];
    float sn = sinb[spos * HD_ + lane];
    size_t o;
    if (HEAD_MAJOR) {
        int b = tok >> 11, s = tok & (S_ - 1);
        o = ((size_t)(b * NHEADS + head) * S_ + s) * HD_;
    } else {
        o = ((size_t)tok * NHEADS + head) * HD_;
    }
    out[o + lane]      = f2bf(n1 * c - n2 * sn);
    out[o + lane + 64] = f2bf(n2 * c + n1 * sn);
}

// ---------------------------------------------------------------------------
// V slice of qkv (bf16, at column VOFF_) -> bf16 (b,g,d,s).
// ---------------------------------------------------------------------------
__global__ __launch_bounds__(256) void vtrans_kernel(const short* __restrict__ qkv,
                                                     short* __restrict__ vt) {
    size_t idx = (size_t)blockIdx.x * 256 + threadIdx.x;  // (b,g,d,s)
    int s  = idx & (S_ - 1);
    size_t r = idx >> 11;
    int d  = r & (HD_ - 1);
    size_t r2 = r >> 7;
    int g  = r2 & (NKV_ - 1);
    int b  = (int)(r2 >> 2);
    vt[idx] = qkv[(size_t)(b * S_ + s) * NQKV_ + VOFF_ + g * HD_ + d];
}

// ---------------------------------------------------------------------------
// Flash-style causal GQA attention, LDS-staged K/V (double-buffered,
// global_load_lds w16, xor chunk swizzle). Grid (32,16,2), 256 thr, 64 Q rows.
// qr: (b,s,h,hd)  kg: (b,g,s,hd)  vt: (b,g,hd,s)  aout: (b,s,h,hd) bf16
// ---------------------------------------------------------------------------
__global__ __launch_bounds__(256) void attn_kernel(const short* __restrict__ qr,
                                                   const short* __restrict__ kg,
                                                   const short* __restrict__ vt,
                                                   short* __restrict__ aout) {
    constexpr int LP = 72;
    __shared__ short Ks[2][64 * 128];   // [key][16 chunks], chunk c at slot c ^ (key&15)
    __shared__ short Vs[2][128 * 64];   // [d][8 chunks],    chunk c at slot c ^ (d&7)
    __shared__ short Pbuf[4 * 16 * LP];

    const int qt = (S_ / 64 - 1) - blockIdx.x;   // big tiles launch first
    const int h = blockIdx.y, b = blockIdx.z;
    const int wave = threadIdx.x >> 6, lane = threadIdx.x & 63;
    const int quad = lane >> 4, l16 = lane & 15;
    const int g  = h >> 2;
    const int q0 = qt * 64 + wave * 16;

    const short* kbase = kg + (size_t)(b * NKV_ + g) * S_ * HD_;
    const short* vbase = vt + (size_t)(b * NKV_ + g) * HD_ * S_;

    bf16x8 qf[4];
    {
        const short* qrow = qr + ((size_t)(b * S_ + q0 + l16) * NH_ + h) * HD_;
        for (int ks = 0; ks < 4; ++ks)
            qf[ks] = *(const bf16x8*)(qrow + ks * 32 + quad * 8);
    }

    f32x4 o[8];
    for (int i = 0; i < 8; ++i) o[i] = (f32x4){0.f, 0.f, 0.f, 0.f};
    float m_i[4] = {-INFINITY, -INFINITY, -INFINITY, -INFINITY};
    float l_i[4] = {0.f, 0.f, 0.f, 0.f};

    short* pw = Pbuf + wave * 16 * LP;

    auto stage = [&](int kt, int bsel) {
        const short* kt_base = kbase + (size_t)kt * 64 * HD_;
        const short* vt_base = vbase + kt * 64;
        for (int t = 0; t < 4; ++t) {
            int ci  = (wave * 4 + t) * 64 + lane;   // 0..1023
            int key = ci >> 4;
            int c   = (ci & 15) ^ (key & 15);
            async16(kt_base + key * HD_ + c * 8, &Ks[bsel][ci * 8]);
        }
        for (int t = 0; t < 4; ++t) {
            int ci = (wave * 4 + t) * 64 + lane;    // 0..1023
            int d  = ci >> 3;
            int c  = (ci & 7) ^ (d & 7);
            async16(vt_base + (size_t)d * S_ + c * 8, &Vs[bsel][ci * 8]);
        }
    };

    stage(0, 0);
    int buf = 0;
    for (int kt = 0; kt <= qt; ++kt) {
        __syncthreads();                 // tile[buf] ready (vmcnt drained)
        if (kt < qt) stage(kt + 1, buf ^ 1);

        // ---- S = Q K^T * scale ----
        float st[4][4];
        for (int nt = 0; nt < 4; ++nt) {
            f32x4 acc = (f32x4){0.f, 0.f, 0.f, 0.f};
            int key = nt * 16 + l16;
            const short* kp = &Ks[buf][key * 128];
            for (int ks = 0; ks < 4; ++ks) {
                int cw = ks * 4 + quad;
                bf16x8 kf = *(const bf16x8*)(kp + ((cw ^ (key & 15)) * 8));
                acc = __builtin_amdgcn_mfma_f32_16x16x32_bf16(qf[ks], kf, acc, 0, 0, 0);
            }
            for (int j = 0; j < 4; ++j) st[nt][j] = acc[j] * SCALE_;
        }
        if (kt == qt) {       // causal mask on diagonal tile
            int rloc = wave * 16 + quad * 4;
            for (int nt = 0; nt < 4; ++nt) {
                int cloc = nt * 16 + l16;
                for (int j = 0; j < 4; ++j)
                    if (cloc > rloc + j) st[nt][j] = -INFINITY;
            }
        }
        // ---- online softmax ----
        float alpha[4];
        for (int j = 0; j < 4; ++j) {
            float m = fmaxf(fmaxf(st[0][j], st[1][j]), fmaxf(st[2][j], st[3][j]));
            m = fmaxf(m, m_i[j]);
            for (int off = 1; off < 16; off <<= 1) m = fmaxf(m, __shfl_xor(m, off));
            alpha[j] = __expf(m_i[j] - m);
            m_i[j] = m;
            float rs = 0.f;
            for (int nt = 0; nt < 4; ++nt) {
                float p = __expf(st[nt][j] - m);
                st[nt][j] = p;
                rs += p;
            }
            for (int off = 1; off < 16; off <<= 1) rs += __shfl_xor(rs, off);
            l_i[j] = alpha[j] * l_i[j] + rs;
        }
        for (int d8 = 0; d8 < 8; ++d8)
            for (int j = 0; j < 4; ++j) o[d8][j] *= alpha[j];
        // ---- P: C-layout -> LDS -> A-layout ----
        for (int nt = 0; nt < 4; ++nt)
            for (int j = 0; j < 4; ++j)
                pw[(quad * 4 + j) * LP + nt * 16 + l16] = f2bf(st[nt][j]);
        // ---- O += P V ----
        for (int ks2 = 0; ks2 < 2; ++ks2) {
            bf16x8 pf = *(const bf16x8*)(pw + l16 * LP + ks2 * 32 + quad * 8);
            for (int d8 = 0; d8 < 8; ++d8) {
                int d = d8 * 16 + l16;
                int cw = ks2 * 4 + quad;
                bf16x8 vf = *(const bf16x8*)&Vs[buf][d * 64 + ((cw ^ (d & 7)) * 8)];
                o[d8] = __builtin_amdgcn_mfma_f32_16x16x32_bf16(pf, vf, o[d8], 0, 0, 0);
            }
        }
        buf ^= 1;
    }
    // ---- normalize + store bf16 (b,s,h,hd) ----
    float inv_l[4];
    for (int j = 0; j < 4; ++j) inv_l[j] = 1.0f / l_i[j];
    for (int d8 = 0; d8 < 8; ++d8)
        for (int j = 0; j < 4; ++j) {
            size_t tok = (size_t)(b * S_ + q0 + quad * 4 + j);
            aout[(tok * NH_ + h) * HD_ + d8 * 16 + l16] = f2bf(o[d8][j] * inv_l[j]);
        }
}

// ---------------------------------------------------------------------------
extern "C" void kernel_launch(void* const* d_in, const int* in_sizes, int n_in,
                              void* d_out, int out_size, void* d_ws, size_t ws_size,
                              hipStream_t stream) {
    (void)in_sizes; (void)n_in; (void)out_size; (void)ws_size;
    const float* x    = (const float*)d_in[0];
    const float* cosb = (const float*)d_in[1];
    const float* sinb = (const float*)d_in[2];
    const float* Wq   = (const float*)d_in[3];
    const float* Wk   = (const float*)d_in[4];
    const float* Wv   = (const float*)d_in[5];
    const float* Wo   = (const float*)d_in[6];
    const float* qw   = (const float*)d_in[7];
    const float* kw   = (const float*)d_in[8];
    float* out = (float*)d_out;

    char* ws = (char*)d_ws;
    short* qkv    = (short*)ws;  ws += (size_t)4096 * NQKV_ * 2;   // 24MB bf16
    short* xb     = (short*)ws;  ws += (size_t)4096 * 2048 * 2;    // 16MB
    short* Wt     = (short*)ws;  ws += (size_t)NQKV_ * 2048 * 2;   // 12MB [n][k]
    short* Wot    = (short*)ws;  ws += (size_t)2048 * 2048 * 2;    // 8MB  [n][k]
    short* q_rope = (short*)ws;  ws += (size_t)4096 * 2048 * 2;    // 16MB (b,s,h,hd)
    short* k_rope = (short*)ws;  ws += (size_t)4096 * 512 * 2;     // 4MB  (b,g,s,hd)
    short* vt     = (short*)ws;  ws += (size_t)4096 * 512 * 2;     // 4MB  (b,g,hd,s)
    short* a_out  = (short*)ws;  ws += (size_t)4096 * 2048 * 2;    // 16MB

    const int M = B_ * S_;  // 4096

    // pre-pass: bf16 casts + weight transposes
    cast_kernel<<<M * 2048 / 1024, 256, 0, stream>>>(x, xb);
    transpose_cast_kernel<<<dim3(2048 / 64, 2048 / 64), 256, 0, stream>>>(Wq, Wt, 2048, 2048);
    transpose_cast_kernel<<<dim3(512 / 64, 2048 / 64), 256, 0, stream>>>(Wk, Wt + (size_t)KOFF_ * 2048, 2048, 512);
    transpose_cast_kernel<<<dim3(512 / 64, 2048 / 64), 256, 0, stream>>>(Wv, Wt + (size_t)VOFF_ * 2048, 2048, 512);
    transpose_cast_kernel<<<dim3(2048 / 64, 2048 / 64), 256, 0, stream>>>(Wo, Wot, 2048, 2048);

    // fused QKV projection: [4096][2048] @ [2048][3072] -> bf16 [4096][3072]
    gemm_tt_kernel<short><<<dim3(NQKV_ / 128, M / 128), 256, 0, stream>>>(
        xb, Wt, qkv, M, NQKV_, 2048);

    // RMSNorm + RoPE; V transpose
    rope_rms_kernel<NH_, false><<<M * NH_ / 4, 256, 0, stream>>>(qkv, 0, cosb, sinb, qw, q_rope);
    rope_rms_kernel<NKV_, true><<<M * NKV_ / 4, 256, 0, stream>>>(qkv, KOFF_, cosb, sinb, kw, k_rope);
    vtrans_kernel<<<(size_t)B_ * NKV_ * HD_ * S_ / 256, 256, 0, stream>>>(qkv, vt);

    // causal GQA flash attention
    attn_kernel<<<dim3(S_ / 64, NH_, B_), 256, 0, stream>>>(q_rope, k_rope, vt, a_out);

    // output projection: [4096][2048] @ [2048][2048] -> fp32 out
    gemm_tt_kernel<float><<<dim3(D_ / 128, M / 128), 256, 0, stream>>>(
        a_out, Wot, out, M, D_, 2048);
}

// Round 4
// 358.390 us; speedup vs baseline: 3.3853x; 1.2382x over previous
//
#include <hip/hip_runtime.h>
#include <hip/hip_bf16.h>
#include <math.h>

#define B_ 2
#define S_ 2048
#define D_ 2048
#define NH_ 16
#define NKV_ 4
#define HD_ 128
#define EPS_ 1e-6f
#define SCALE_ 0.08838834764831845f  // 1/sqrt(128)
#define LOG2E_ 1.4426950408889634f
#define NQKV_ 3072                   // fused QKV output width
#define KOFF_ 2048                   // k slice column offset in fused qkv
#define VOFF_ 2560                   // v slice column offset in fused qkv

typedef float f32x4 __attribute__((ext_vector_type(4)));
typedef short bf16x8 __attribute__((ext_vector_type(8)));
typedef short short4v __attribute__((ext_vector_type(4)));
typedef float float4v __attribute__((ext_vector_type(4)));
typedef unsigned uint2v __attribute__((ext_vector_type(2)));

static __device__ __forceinline__ short f2bf(float f) {
    union { float f; unsigned u; } x{f};
    unsigned r = (x.u + 0x7fff + ((x.u >> 16) & 1)) >> 16;   // RTNE
    return (short)r;
}
static __device__ __forceinline__ float bf2f(short s) {
    union { unsigned u; float f; } x; x.u = ((unsigned)(unsigned short)s) << 16; return x.f;
}
// pack two fp32 -> two bf16 (truncation) in ONE v_perm: lo16=hi16(a), hi16=hi16(b)
static __device__ __forceinline__ unsigned pack_bf2(float a, float b) {
    return __builtin_amdgcn_perm(__builtin_bit_cast(unsigned, b),
                                 __builtin_bit_cast(unsigned, a), 0x07060302u);
}

#define AS1(p) ((const __attribute__((address_space(1))) void*)(p))
#define AS3(p) ((__attribute__((address_space(3))) void*)(p))
static __device__ __forceinline__ void async16(const void* g, void* l) {
    __builtin_amdgcn_global_load_lds(AS1(g), AS3(l), 16, 0, 0);
}

// ---------------------------------------------------------------------------
// fp32 -> bf16 flat cast (for x). 4 elems/thread.
// ---------------------------------------------------------------------------
__global__ __launch_bounds__(256) void cast_kernel(const float* __restrict__ in,
                                                   short* __restrict__ out) {
    size_t i = ((size_t)blockIdx.x * 256 + threadIdx.x) * 4;
    float4v v = *(const float4v*)(in + i);
    short4v o; o.x = f2bf(v.x); o.y = f2bf(v.y); o.z = f2bf(v.z); o.w = f2bf(v.w);
    *(short4v*)(out + i) = o;
}

// ---------------------------------------------------------------------------
// fp32 [K][N] -> bf16 [N][K] transpose+cast. 64x64 tiles, 256 threads.
// ---------------------------------------------------------------------------
__global__ __launch_bounds__(256) void transpose_cast_kernel(const float* __restrict__ in,
                                                             short* __restrict__ out,
                                                             int K, int N) {
    __shared__ float tile[64][65];
    const int n0 = blockIdx.x * 64, k0 = blockIdx.y * 64;
    const int tid = threadIdx.x;
    for (int r = 0; r < 16; ++r) {
        int k = r * 4 + (tid >> 6);
        int n = tid & 63;
        tile[k][n] = in[(size_t)(k0 + k) * N + n0 + n];
    }
    __syncthreads();
    for (int r = 0; r < 16; ++r) {
        int n = r * 4 + (tid >> 6);
        int k = tid & 63;
        out[(size_t)(n0 + n) * K + k0 + k] = f2bf(tile[k][n]);
    }
}

// ---------------------------------------------------------------------------
// m97-style GEMM: C[M][N] = A[M][K] @ Bt[N][K]^T, A/Bt bf16, C fp32 or bf16.
// 128x128 tile, BK=32, global_load_lds width-16, rotation-swizzled LDS chunks.
// ---------------------------------------------------------------------------
template<typename TC>
__global__ __launch_bounds__(256) void gemm_tt_kernel(const short* __restrict__ A,
                                                      const short* __restrict__ Bt,
                                                      TC* __restrict__ C,
                                                      int M, int N, int K) {
    __shared__ short As[128 * 32];   // [row][4 chunks of 8 bf16], chunk c at slot (c + (r>>1))&3
    __shared__ short Bs[128 * 32];

    const int tid  = threadIdx.x;
    const int bn   = blockIdx.x, bm = blockIdx.y;
    const int wave = tid >> 6, lane = tid & 63;
    const int quad = lane >> 4, l16 = lane & 15;
    const int wr = wave >> 1, wc = wave & 1;

    f32x4 acc[4][4];
    for (int i = 0; i < 4; ++i)
        for (int j = 0; j < 4; ++j) acc[i][j] = (f32x4){0.f, 0.f, 0.f, 0.f};

    const short* Abase = A  + (size_t)(bm * 128) * K;
    const short* Bbase = Bt + (size_t)(bn * 128) * K;

    int ci0 = wave * 128 + lane;
    for (int k0 = 0; k0 < K; k0 += 32) {
        __syncthreads();
        for (int t = 0; t < 2; ++t) {
            int ci = ci0 + t * 64;          // 0..511
            int r  = ci >> 2;
            int c  = ((ci & 3) - (r >> 1)) & 3;
            size_t goff = (size_t)r * K + k0 + c * 8;
            async16(Abase + goff, &As[ci * 8]);
            async16(Bbase + goff, &Bs[ci * 8]);
        }
        __syncthreads();

        bf16x8 af[4], bfv[4];
        for (int mt = 0; mt < 4; ++mt) {
            int r = wr * 64 + mt * 16 + l16;
            af[mt] = *(const bf16x8*)&As[r * 32 + (((quad + (r >> 1)) & 3) * 8)];
        }
        for (int nt = 0; nt < 4; ++nt) {
            int r = wc * 64 + nt * 16 + l16;
            bfv[nt] = *(const bf16x8*)&Bs[r * 32 + (((quad + (r >> 1)) & 3) * 8)];
        }
        for (int mt = 0; mt < 4; ++mt)
            for (int nt = 0; nt < 4; ++nt)
                acc[mt][nt] = __builtin_amdgcn_mfma_f32_16x16x32_bf16(
                    af[mt], bfv[nt], acc[mt][nt], 0, 0, 0);
    }

    for (int mt = 0; mt < 4; ++mt)
        for (int nt = 0; nt < 4; ++nt)
            for (int j = 0; j < 4; ++j) {
                int row = bm * 128 + wr * 64 + mt * 16 + quad * 4 + j;
                int col = bn * 128 + wc * 64 + nt * 16 + l16;
                float v = acc[mt][nt][j];
                if constexpr (__is_same(TC, short))
                    C[(size_t)row * N + col] = f2bf(v);
                else
                    C[(size_t)row * N + col] = v;
            }
}

// ---------------------------------------------------------------------------
// RMSNorm + RoPE from bf16 qkv rows. 4 rows per 256-block (1/wave).
// HEAD_MAJOR=false: out (b,s,head,hd); true: out (b,head,s,hd).
// outscale folds attention logit scaling (in exp2 basis) into Q.
// ---------------------------------------------------------------------------
template<int NHEADS, bool HEAD_MAJOR>
__global__ __launch_bounds__(256) void rope_rms_kernel(const short* __restrict__ qkv,
                                                       int coloff,
                                                       const float* __restrict__ cosb,
                                                       const float* __restrict__ sinb,
                                                       const float* __restrict__ w,
                                                       short* __restrict__ out,
                                                       float outscale) {
    const int r    = blockIdx.x * 4 + (threadIdx.x >> 6);  // token*NHEADS + head
    const int lane = threadIdx.x & 63;
    const int tok  = r / NHEADS, head = r % NHEADS;
    const int spos = tok & (S_ - 1);
    const short* row = qkv + (size_t)tok * NQKV_ + coloff + head * HD_;
    float h1 = bf2f(row[lane]), h2 = bf2f(row[lane + 64]);
    float ss = h1 * h1 + h2 * h2;
    for (int off = 1; off < 64; off <<= 1) ss += __shfl_xor(ss, off);
    float rstd = rsqrtf(ss * (1.0f / HD_) + EPS_);
    float n1 = h1 * rstd * w[lane];
    float n2 = h2 * rstd * w[lane + 64];
    float c  = cosb[spos * HD_ + lane];
    float sn = sinb[spos * HD_ + lane];
    size_t o;
    if (HEAD_MAJOR) {
        int b = tok >> 11, s = tok & (S_ - 1);
        o = ((size_t)(b * NHEADS + head) * S_ + s) * HD_;
    } else {
        o = ((size_t)tok * NHEADS + head) * HD_;
    }
    out[o + lane]      = f2bf((n1 * c - n2 * sn) * outscale);
    out[o + lane + 64] = f2bf((n2 * c + n1 * sn) * outscale);
}

// ---------------------------------------------------------------------------
// V slice of qkv (bf16, at column VOFF_) -> bf16 (b,g,d,s). 64x64 LDS tiles.
// grid (S/64, HD/64, B*NKV)
// ---------------------------------------------------------------------------
__global__ __launch_bounds__(256) void vtrans_kernel(const short* __restrict__ qkv,
                                                     short* __restrict__ vt) {
    __shared__ short tile[64][71];   // odd-ish pad: ~2-way banks both phases
    const int s0 = blockIdx.x * 64, d0 = blockIdx.y * 64;
    const int g = blockIdx.z & 3, b = blockIdx.z >> 2;
    const int tid = threadIdx.x;
    for (int r = 0; r < 16; ++r) {
        int s = r * 4 + (tid >> 6);
        int d = tid & 63;
        tile[s][d] = qkv[(size_t)(b * S_ + s0 + s) * NQKV_ + VOFF_ + g * HD_ + d0 + d];
    }
    __syncthreads();
    for (int r = 0; r < 16; ++r) {
        int d = r * 4 + (tid >> 6);
        int s = tid & 63;
        vt[((size_t)(b * NKV_ + g) * HD_ + d0 + d) * S_ + s0 + s] = tile[s][d];
    }
}

// ---------------------------------------------------------------------------
// Flash-style causal GQA attention, S^T formulation (per-lane softmax rows),
// 2 heads per block sharing K/V LDS tiles. Grid 512 x 256 threads.
// qr: (b,s,h,hd) pre-scaled by SCALE*log2e; kg: (b,g,s,hd); vt: (b,g,hd,s)
// aout: (b,s,h,hd) bf16.
// ---------------------------------------------------------------------------
__global__ __launch_bounds__(256, 2) void attn_kernel(const short* __restrict__ qr,
                                                      const short* __restrict__ kg,
                                                      const short* __restrict__ vt,
                                                      short* __restrict__ aout) {
    __shared__ short Ks[2][64 * 128];   // [key][16 chunks], chunk c at slot c ^ (key&15)
    __shared__ short Vs[2][128 * 64];   // [d][8 chunks],    chunk c at slot c ^ (d&7)

    // decode + qt-pairing swizzle: blocks n and n+256 get qt and 31-qt
    const int lin   = blockIdx.x;
    const int qslot = lin & 31;
    const int ybidx = lin >> 5;                       // 0..15
    const int qt    = (ybidx & 8) ? qslot : 31 - qslot;
    const int b  = ybidx & 1;
    const int g  = (ybidx >> 1) & 3;
    const int hp = (ybidx >> 3) & 1;
    const int h0 = g * 4 + hp * 2;                    // this block: heads h0, h0+1

    const int wave = threadIdx.x >> 6, lane = threadIdx.x & 63;
    const int quad = lane >> 4, l16 = lane & 15;
    const int qrow = qt * 64 + wave * 16 + l16;       // this lane's q position

    const short* kbase = kg + (size_t)(b * NKV_ + g) * S_ * HD_;
    const short* vbase = vt + (size_t)(b * NKV_ + g) * HD_ * S_;

    // Q fragments (B-operand layout): lane holds row qrow, k = ks*32+quad*8+j
    bf16x8 qf[2][4];
    for (int hh = 0; hh < 2; ++hh) {
        const short* qp = qr + ((size_t)(b * S_ + qrow) * NH_ + h0 + hh) * HD_;
        for (int ks = 0; ks < 4; ++ks)
            qf[hh][ks] = *(const bf16x8*)(qp + ks * 32 + quad * 8);
    }

    f32x4 o[2][8];    // O^T: D[m=d][n=qrow]; lane: d = d8*16 + quad*4 + j
    for (int hh = 0; hh < 2; ++hh)
        for (int i = 0; i < 8; ++i) o[hh][i] = (f32x4){0.f, 0.f, 0.f, 0.f};
    float m_i[2] = {-INFINITY, -INFINITY};
    float l_i[2] = {0.f, 0.f};

    auto stage = [&](int kt, int bsel) {
        const short* kt_base = kbase + (size_t)kt * 64 * HD_;
        const short* vt_base = vbase + kt * 64;
        for (int t = 0; t < 4; ++t) {
            int ci  = (wave * 4 + t) * 64 + lane;   // 0..1023
            int key = ci >> 4;
            int c   = (ci & 15) ^ (key & 15);
            async16(kt_base + key * HD_ + c * 8, &Ks[bsel][ci * 8]);
        }
        for (int t = 0; t < 4; ++t) {
            int ci = (wave * 4 + t) * 64 + lane;    // 0..1023
            int d  = ci >> 3;
            int c  = (ci & 7) ^ (d & 7);
            async16(vt_base + (size_t)d * S_ + c * 8, &Vs[bsel][ci * 8]);
        }
    };

    stage(0, 0);
    int buf = 0;
    for (int kt = 0; kt <= qt; ++kt) {
        __syncthreads();                 // tile[buf] ready
        if (kt < qt) stage(kt + 1, buf ^ 1);

        // ---- S^T = K·Q^T (per m-tile nt, permuted keys) ----
        // phys key for tile nt, m-index i: (nt>>1)*32 + (i>>2)*8 + (nt&1)*4 + (i&3)
        f32x4 acc[2][4];
        for (int hh = 0; hh < 2; ++hh)
            for (int nt = 0; nt < 4; ++nt) acc[hh][nt] = (f32x4){0.f, 0.f, 0.f, 0.f};
        for (int nt = 0; nt < 4; ++nt) {
            int prow = ((nt >> 1) << 5) + ((l16 >> 2) << 3) + ((nt & 1) << 2) + (l16 & 3);
            const short* kp = &Ks[buf][prow * 128];
            int pm = prow & 15;
            for (int ks = 0; ks < 4; ++ks) {
                bf16x8 kf = *(const bf16x8*)(kp + (((ks * 4 + quad) ^ pm) * 8));
                acc[0][nt] = __builtin_amdgcn_mfma_f32_16x16x32_bf16(kf, qf[0][ks], acc[0][nt], 0, 0, 0);
                acc[1][nt] = __builtin_amdgcn_mfma_f32_16x16x32_bf16(kf, qf[1][ks], acc[1][nt], 0, 0, 0);
            }
        }
        // causal mask (diagonal tile): D row quad*4+j -> phys key
        if (kt == qt) {
            int rl = wave * 16 + l16;
            for (int nt = 0; nt < 4; ++nt)
                for (int j = 0; j < 4; ++j) {
                    int kl = ((nt >> 1) << 5) + (quad << 3) + ((nt & 1) << 2) + j;
                    if (kl > rl) { acc[0][nt][j] = -INFINITY; acc[1][nt][j] = -INFINITY; }
                }
        }
        // ---- online softmax (per-lane row) + pack P into PV B-fragments ----
        unsigned pk[2][2][4];   // [head][key-group][dword]
        for (int hh = 0; hh < 2; ++hh) {
            float mx = m_i[hh];
            for (int nt = 0; nt < 4; ++nt)
                for (int j = 0; j < 4; ++j) mx = fmaxf(mx, acc[hh][nt][j]);
            mx = fmaxf(mx, __shfl_xor(mx, 16));
            mx = fmaxf(mx, __shfl_xor(mx, 32));
            float al = exp2f(m_i[hh] - mx);
            m_i[hh] = mx;
            float rs = 0.f;
            float p[4][4];
            for (int nt = 0; nt < 4; ++nt)
                for (int j = 0; j < 4; ++j) {
                    float e = exp2f(acc[hh][nt][j] - mx);
                    p[nt][j] = e;
                    rs += e;
                }
            rs += __shfl_xor(rs, 16);
            rs += __shfl_xor(rs, 32);
            l_i[hh] = al * l_i[hh] + rs;
            for (int d8 = 0; d8 < 8; ++d8)
                for (int j = 0; j < 4; ++j) o[hh][d8][j] *= al;
            // B-frag key-group grp (32 keys): k-idx quad*8+j' -> nt=2grp (j'=0..3), nt=2grp+1 (j'=4..7)
            for (int grp = 0; grp < 2; ++grp) {
                pk[hh][grp][0] = pack_bf2(p[2 * grp][0],     p[2 * grp][1]);
                pk[hh][grp][1] = pack_bf2(p[2 * grp][2],     p[2 * grp][3]);
                pk[hh][grp][2] = pack_bf2(p[2 * grp + 1][0], p[2 * grp + 1][1]);
                pk[hh][grp][3] = pack_bf2(p[2 * grp + 1][2], p[2 * grp + 1][3]);
            }
        }
        // ---- O^T += V^T · P^T ----
        for (int grp = 0; grp < 2; ++grp) {
            union { unsigned u[4]; bf16x8 v; } pb0, pb1;
            for (int i = 0; i < 4; ++i) { pb0.u[i] = pk[0][grp][i]; pb1.u[i] = pk[1][grp][i]; }
            for (int d8 = 0; d8 < 8; ++d8) {
                int d = d8 * 16 + l16;
                bf16x8 vf = *(const bf16x8*)&Vs[buf][d * 64 + (((grp * 4 + quad) ^ (d & 7)) * 8)];
                o[0][d8] = __builtin_amdgcn_mfma_f32_16x16x32_bf16(vf, pb0.v, o[0][d8], 0, 0, 0);
                o[1][d8] = __builtin_amdgcn_mfma_f32_16x16x32_bf16(vf, pb1.v, o[1][d8], 0, 0, 0);
            }
        }
        buf ^= 1;
    }
    // ---- normalize + store bf16 (b,s,h,hd): lane writes 4 consecutive d (8B) ----
    for (int hh = 0; hh < 2; ++hh) {
        float il = 1.0f / l_i[hh];
        short* op = aout + ((size_t)(b * S_ + qrow) * NH_ + h0 + hh) * HD_ + quad * 4;
        for (int d8 = 0; d8 < 8; ++d8) {
            uint2v w;
            w.x = ((unsigned)(unsigned short)f2bf(o[hh][d8][0] * il)) |
                  ((unsigned)(unsigned short)f2bf(o[hh][d8][1] * il) << 16);
            w.y = ((unsigned)(unsigned short)f2bf(o[hh][d8][2] * il)) |
                  ((unsigned)(unsigned short)f2bf(o[hh][d8][3] * il) << 16);
            *(uint2v*)(op + d8 * 16) = w;
        }
    }
}

// ---------------------------------------------------------------------------
extern "C" void kernel_launch(void* const* d_in, const int* in_sizes, int n_in,
                              void* d_out, int out_size, void* d_ws, size_t ws_size,
                              hipStream_t stream) {
    (void)in_sizes; (void)n_in; (void)out_size; (void)ws_size;
    const float* x    = (const float*)d_in[0];
    const float* cosb = (const float*)d_in[1];
    const float* sinb = (const float*)d_in[2];
    const float* Wq   = (const float*)d_in[3];
    const float* Wk   = (const float*)d_in[4];
    const float* Wv   = (const float*)d_in[5];
    const float* Wo   = (const float*)d_in[6];
    const float* qw   = (const float*)d_in[7];
    const float* kw   = (const float*)d_in[8];
    float* out = (float*)d_out;

    char* ws = (char*)d_ws;
    short* qkv    = (short*)ws;  ws += (size_t)4096 * NQKV_ * 2;   // 24MB bf16
    short* xb     = (short*)ws;  ws += (size_t)4096 * 2048 * 2;    // 16MB
    short* Wt     = (short*)ws;  ws += (size_t)NQKV_ * 2048 * 2;   // 12MB [n][k]
    short* Wot    = (short*)ws;  ws += (size_t)2048 * 2048 * 2;    // 8MB  [n][k]
    short* q_rope = (short*)ws;  ws += (size_t)4096 * 2048 * 2;    // 16MB (b,s,h,hd)
    short* k_rope = (short*)ws;  ws += (size_t)4096 * 512 * 2;     // 4MB  (b,g,s,hd)
    short* vt     = (short*)ws;  ws += (size_t)4096 * 512 * 2;     // 4MB  (b,g,hd,s)
    short* a_out  = (short*)ws;  ws += (size_t)4096 * 2048 * 2;    // 16MB

    const int M = B_ * S_;  // 4096

    // pre-pass: bf16 casts + weight transposes
    cast_kernel<<<M * 2048 / 1024, 256, 0, stream>>>(x, xb);
    transpose_cast_kernel<<<dim3(2048 / 64, 2048 / 64), 256, 0, stream>>>(Wq, Wt, 2048, 2048);
    transpose_cast_kernel<<<dim3(512 / 64, 2048 / 64), 256, 0, stream>>>(Wk, Wt + (size_t)KOFF_ * 2048, 2048, 512);
    transpose_cast_kernel<<<dim3(512 / 64, 2048 / 64), 256, 0, stream>>>(Wv, Wt + (size_t)VOFF_ * 2048, 2048, 512);
    transpose_cast_kernel<<<dim3(2048 / 64, 2048 / 64), 256, 0, stream>>>(Wo, Wot, 2048, 2048);

    // fused QKV projection: [4096][2048] @ [2048][3072] -> bf16 [4096][3072]
    gemm_tt_kernel<short><<<dim3(NQKV_ / 128, M / 128), 256, 0, stream>>>(
        xb, Wt, qkv, M, NQKV_, 2048);

    // RMSNorm + RoPE (Q pre-scaled into exp2 basis); V transpose
    rope_rms_kernel<NH_, false><<<M * NH_ / 4, 256, 0, stream>>>(
        qkv, 0, cosb, sinb, qw, q_rope, SCALE_ * LOG2E_);
    rope_rms_kernel<NKV_, true><<<M * NKV_ / 4, 256, 0, stream>>>(
        qkv, KOFF_, cosb, sinb, kw, k_rope, 1.0f);
    vtrans_kernel<<<dim3(S_ / 64, HD_ / 64, B_ * NKV_), 256, 0, stream>>>(qkv, vt);

    // causal GQA flash attention (2 heads/block, qt-paired)
    attn_kernel<<<512, 256, 0, stream>>>(q_rope, k_rope, vt, a_out);

    // output projection: [4096][2048] @ [2048][2048] -> fp32 out
    gemm_tt_kernel<float><<<dim3(D_ / 128, M / 128), 256, 0, stream>>>(
        a_out, Wot, out, M, D_, 2048);
}

// Round 5
// 337.063 us; speedup vs baseline: 3.5995x; 1.0633x over previous
//
#include <hip/hip_runtime.h>
#include <hip/hip_bf16.h>
#include <math.h>

#define B_ 2
#define S_ 2048
#define D_ 2048
#define NH_ 16
#define NKV_ 4
#define HD_ 128
#define EPS_ 1e-6f
#define SCALE_ 0.08838834764831845f  // 1/sqrt(128)
#define LOG2E_ 1.4426950408889634f
#define NQKV_ 3072                   // fused QKV output width
#define KOFF_ 2048                   // k slice column offset in fused qkv
#define VOFF_ 2560                   // v slice column offset in fused qkv

typedef float f32x4 __attribute__((ext_vector_type(4)));
typedef short bf16x8 __attribute__((ext_vector_type(8)));
typedef short short4v __attribute__((ext_vector_type(4)));
typedef float float4v __attribute__((ext_vector_type(4)));
typedef unsigned uint2v __attribute__((ext_vector_type(2)));

static __device__ __forceinline__ short f2bf(float f) {
    union { float f; unsigned u; } x{f};
    unsigned r = (x.u + 0x7fff + ((x.u >> 16) & 1)) >> 16;   // RTNE
    return (short)r;
}
static __device__ __forceinline__ float bf2f(short s) {
    union { unsigned u; float f; } x; x.u = ((unsigned)(unsigned short)s) << 16; return x.f;
}
// pack two fp32 -> two bf16 (truncation) in ONE v_perm: lo16=hi16(a), hi16=hi16(b)
static __device__ __forceinline__ unsigned pack_bf2(float a, float b) {
    return __builtin_amdgcn_perm(__builtin_bit_cast(unsigned, b),
                                 __builtin_bit_cast(unsigned, a), 0x07060302u);
}

#define AS1(p) ((const __attribute__((address_space(1))) void*)(p))
#define AS3(p) ((__attribute__((address_space(3))) void*)(p))
static __device__ __forceinline__ void async16(const void* g, void* l) {
    __builtin_amdgcn_global_load_lds(AS1(g), AS3(l), 16, 0, 0);
}

// ---------------------------------------------------------------------------
// fp32 -> bf16 flat cast (for x). 4 elems/thread.
// ---------------------------------------------------------------------------
__global__ __launch_bounds__(256) void cast_kernel(const float* __restrict__ in,
                                                   short* __restrict__ out) {
    size_t i = ((size_t)blockIdx.x * 256 + threadIdx.x) * 4;
    float4v v = *(const float4v*)(in + i);
    short4v o; o.x = f2bf(v.x); o.y = f2bf(v.y); o.z = f2bf(v.z); o.w = f2bf(v.w);
    *(short4v*)(out + i) = o;
}

// ---------------------------------------------------------------------------
// fp32 [K][N] -> bf16 [N][K] transpose+cast. 64x64 tiles, 256 threads.
// ---------------------------------------------------------------------------
__global__ __launch_bounds__(256) void transpose_cast_kernel(const float* __restrict__ in,
                                                             short* __restrict__ out,
                                                             int K, int N) {
    __shared__ float tile[64][65];
    const int n0 = blockIdx.x * 64, k0 = blockIdx.y * 64;
    const int tid = threadIdx.x;
    for (int r = 0; r < 16; ++r) {
        int k = r * 4 + (tid >> 6);
        int n = tid & 63;
        tile[k][n] = in[(size_t)(k0 + k) * N + n0 + n];
    }
    __syncthreads();
    for (int r = 0; r < 16; ++r) {
        int n = r * 4 + (tid >> 6);
        int k = tid & 63;
        out[(size_t)(n0 + n) * K + k0 + k] = f2bf(tile[k][n]);
    }
}

// ---------------------------------------------------------------------------
// m97-style GEMM: C[M][N] = A[M][K] @ Bt[N][K]^T, A/Bt bf16, C fp32 or bf16.
// 128x128 tile, BK=32, global_load_lds width-16, rotation-swizzled LDS chunks.
// ---------------------------------------------------------------------------
template<typename TC>
__global__ __launch_bounds__(256) void gemm_tt_kernel(const short* __restrict__ A,
                                                      const short* __restrict__ Bt,
                                                      TC* __restrict__ C,
                                                      int M, int N, int K) {
    __shared__ short As[128 * 32];   // [row][4 chunks of 8 bf16], chunk c at slot (c + (r>>1))&3
    __shared__ short Bs[128 * 32];

    const int tid  = threadIdx.x;
    const int bn   = blockIdx.x, bm = blockIdx.y;
    const int wave = tid >> 6, lane = tid & 63;
    const int quad = lane >> 4, l16 = lane & 15;
    const int wr = wave >> 1, wc = wave & 1;

    f32x4 acc[4][4];
    for (int i = 0; i < 4; ++i)
        for (int j = 0; j < 4; ++j) acc[i][j] = (f32x4){0.f, 0.f, 0.f, 0.f};

    const short* Abase = A  + (size_t)(bm * 128) * K;
    const short* Bbase = Bt + (size_t)(bn * 128) * K;

    int ci0 = wave * 128 + lane;
    for (int k0 = 0; k0 < K; k0 += 32) {
        __syncthreads();
        for (int t = 0; t < 2; ++t) {
            int ci = ci0 + t * 64;          // 0..511
            int r  = ci >> 2;
            int c  = ((ci & 3) - (r >> 1)) & 3;
            size_t goff = (size_t)r * K + k0 + c * 8;
            async16(Abase + goff, &As[ci * 8]);
            async16(Bbase + goff, &Bs[ci * 8]);
        }
        __syncthreads();

        bf16x8 af[4], bfv[4];
        for (int mt = 0; mt < 4; ++mt) {
            int r = wr * 64 + mt * 16 + l16;
            af[mt] = *(const bf16x8*)&As[r * 32 + (((quad + (r >> 1)) & 3) * 8)];
        }
        for (int nt = 0; nt < 4; ++nt) {
            int r = wc * 64 + nt * 16 + l16;
            bfv[nt] = *(const bf16x8*)&Bs[r * 32 + (((quad + (r >> 1)) & 3) * 8)];
        }
        for (int mt = 0; mt < 4; ++mt)
            for (int nt = 0; nt < 4; ++nt)
                acc[mt][nt] = __builtin_amdgcn_mfma_f32_16x16x32_bf16(
                    af[mt], bfv[nt], acc[mt][nt], 0, 0, 0);
    }

    for (int mt = 0; mt < 4; ++mt)
        for (int nt = 0; nt < 4; ++nt)
            for (int j = 0; j < 4; ++j) {
                int row = bm * 128 + wr * 64 + mt * 16 + quad * 4 + j;
                int col = bn * 128 + wc * 64 + nt * 16 + l16;
                float v = acc[mt][nt][j];
                if constexpr (__is_same(TC, short))
                    C[(size_t)row * N + col] = f2bf(v);
                else
                    C[(size_t)row * N + col] = v;
            }
}

// ---------------------------------------------------------------------------
// RMSNorm + RoPE from bf16 qkv rows. 4 rows per 256-block (1/wave).
// HEAD_MAJOR=false: out (b,s,head,hd); true: out (b,head,s,hd).
// outscale folds attention logit scaling (in exp2 basis) into Q.
// ---------------------------------------------------------------------------
template<int NHEADS, bool HEAD_MAJOR>
__global__ __launch_bounds__(256) void rope_rms_kernel(const short* __restrict__ qkv,
                                                       int coloff,
                                                       const float* __restrict__ cosb,
                                                       const float* __restrict__ sinb,
                                                       const float* __restrict__ w,
                                                       short* __restrict__ out,
                                                       float outscale) {
    const int r    = blockIdx.x * 4 + (threadIdx.x >> 6);  // token*NHEADS + head
    const int lane = threadIdx.x & 63;
    const int tok  = r / NHEADS, head = r % NHEADS;
    const int spos = tok & (S_ - 1);
    const short* row = qkv + (size_t)tok * NQKV_ + coloff + head * HD_;
    float h1 = bf2f(row[lane]), h2 = bf2f(row[lane + 64]);
    float ss = h1 * h1 + h2 * h2;
    for (int off = 1; off < 64; off <<= 1) ss += __shfl_xor(ss, off);
    float rstd = rsqrtf(ss * (1.0f / HD_) + EPS_);
    float n1 = h1 * rstd * w[lane];
    float n2 = h2 * rstd * w[lane + 64];
    float c  = cosb[spos * HD_ + lane];
    float sn = sinb[spos * HD_ + lane];
    size_t o;
    if (HEAD_MAJOR) {
        int b = tok >> 11, s = tok & (S_ - 1);
        o = ((size_t)(b * NHEADS + head) * S_ + s) * HD_;
    } else {
        o = ((size_t)tok * NHEADS + head) * HD_;
    }
    out[o + lane]      = f2bf((n1 * c - n2 * sn) * outscale);
    out[o + lane + 64] = f2bf((n2 * c + n1 * sn) * outscale);
}

// ---------------------------------------------------------------------------
// V slice of qkv (bf16, at column VOFF_) -> bf16 (b,g,d,s). 64x64 LDS tiles.
// grid (S/64, HD/64, B*NKV)
// ---------------------------------------------------------------------------
__global__ __launch_bounds__(256) void vtrans_kernel(const short* __restrict__ qkv,
                                                     short* __restrict__ vt) {
    __shared__ short tile[64][71];
    const int s0 = blockIdx.x * 64, d0 = blockIdx.y * 64;
    const int g = blockIdx.z & 3, b = blockIdx.z >> 2;
    const int tid = threadIdx.x;
    for (int r = 0; r < 16; ++r) {
        int s = r * 4 + (tid >> 6);
        int d = tid & 63;
        tile[s][d] = qkv[(size_t)(b * S_ + s0 + s) * NQKV_ + VOFF_ + g * HD_ + d0 + d];
    }
    __syncthreads();
    for (int r = 0; r < 16; ++r) {
        int d = r * 4 + (tid >> 6);
        int s = tid & 63;
        vt[((size_t)(b * NKV_ + g) * HD_ + d0 + d) * S_ + s0 + s] = tile[s][d];
    }
}

// ---------------------------------------------------------------------------
// Flash causal GQA attention v3: 256 equal blocks, 512 thr (8 waves, 2/SIMD),
// 1 block/CU (128KB LDS). Each block: qt-pair {pr, 31-pr} done sequentially.
// Per pass: Q-tile 64 rows x 2 heads; 128-key K/V tiles double-buffered;
// waves 0-3 take keys [0,64) of each tile, waves 4-7 keys [64,128)
// (block-level split-K), per-wave (m,l,O) merged through LDS at pass end.
// qr pre-scaled by SCALE*log2e. kg (b,g,s,hd); vt (b,g,hd,s); aout (b,s,h,hd).
// ---------------------------------------------------------------------------
__global__ __launch_bounds__(512, 2) void attn_kernel(const short* __restrict__ qr,
                                                      const short* __restrict__ kg,
                                                      const short* __restrict__ vt,
                                                      short* __restrict__ aout) {
    __shared__ short smem[65536];   // 128KB. Ks: buf*16384; Vs: 32768+buf*16384
    float* fsm = (float*)smem;      // merge overlay (after barriers)

    const int lin = blockIdx.x;
    const int b  = lin & 1;
    const int g  = (lin >> 1) & 3;
    const int hp = (lin >> 3) & 1;
    const int pr = lin >> 4;          // 0..15
    const int h0 = g * 4 + hp * 2;

    const int wave = threadIdx.x >> 6, lane = threadIdx.x & 63;
    const int quad = lane >> 4, l16 = lane & 15;
    const int rw = wave & 3, eh = wave >> 2;   // row-subtile, key-half

    const short* kbase = kg + (size_t)(b * NKV_ + g) * S_ * HD_;
    const short* vbase = vt + (size_t)(b * NKV_ + g) * HD_ * S_;

    for (int pass = 0; pass < 2; ++pass) {
        const int qt    = pass ? (31 - pr) : pr;
        const int iters = (qt >> 1) + 1;
        const int q0    = qt * 64;
        const int qrow  = q0 + rw * 16 + l16;

        bf16x8 qf[2][4];
        for (int hh = 0; hh < 2; ++hh) {
            const short* qp = qr + ((size_t)(b * S_ + qrow) * NH_ + h0 + hh) * HD_;
            for (int ks = 0; ks < 4; ++ks)
                qf[hh][ks] = *(const bf16x8*)(qp + ks * 32 + quad * 8);
        }

        f32x4 o[2][8];
        for (int hh = 0; hh < 2; ++hh)
            for (int i = 0; i < 8; ++i) o[hh][i] = (f32x4){0.f, 0.f, 0.f, 0.f};
        float m_i[2] = {-INFINITY, -INFINITY};
        float l_i[2] = {0.f, 0.f};

        auto stage = [&](int kt, int bsel) {
            const short* kt_base = kbase + (size_t)kt * 128 * HD_;
            const short* vt_base = vbase + kt * 128;
            short* kd = smem + bsel * 16384;
            short* vd = smem + 32768 + bsel * 16384;
            for (int t = 0; t < 4; ++t) {
                int ci  = (wave * 4 + t) * 64 + lane;   // 0..2047
                int row = ci >> 4;
                int c   = (ci & 15) ^ (row & 15);
                async16(kt_base + row * HD_ + c * 8, kd + ci * 8);
                async16(vt_base + (size_t)row * S_ + c * 8, vd + ci * 8);
            }
        };

        stage(0, 0);
        int buf = 0;
        for (int kt = 0; kt < iters; ++kt) {
            __syncthreads();                 // tile[buf] staged & visible
            if (kt + 1 < iters) stage(kt + 1, buf ^ 1);
            const int key_lo = kt * 128 + eh * 64;   // this wave's key-half start
            if (key_lo <= q0 + rw * 16 + 15) {       // wave-uniform: any live key?
                const short* Kb = smem + buf * 16384;
                const short* Vb = smem + 32768 + buf * 16384;
                // ---- S^T = K·Q^T over this wave's 64 keys (permuted m-rows) ----
                f32x4 acc[2][4];
                for (int hh = 0; hh < 2; ++hh)
                    for (int t = 0; t < 4; ++t) acc[hh][t] = (f32x4){0.f, 0.f, 0.f, 0.f};
                for (int t = 0; t < 4; ++t) {
                    int lk = ((t >> 1) << 5) + ((l16 >> 2) << 3) + ((t & 1) << 2) + (l16 & 3);
                    int lr = eh * 64 + lk;           // LDS key row
                    const short* kp = Kb + lr * 128;
                    int pm = lr & 15;
                    for (int ks = 0; ks < 4; ++ks) {
                        bf16x8 kf = *(const bf16x8*)(kp + (((ks * 4 + quad) ^ pm) * 8));
                        acc[0][t] = __builtin_amdgcn_mfma_f32_16x16x32_bf16(kf, qf[0][ks], acc[0][t], 0, 0, 0);
                        acc[1][t] = __builtin_amdgcn_mfma_f32_16x16x32_bf16(kf, qf[1][ks], acc[1][t], 0, 0, 0);
                    }
                }
                if (key_lo + 63 > q0 + rw * 16) {    // diagonal region: causal mask
                    for (int t = 0; t < 4; ++t)
                        for (int j = 0; j < 4; ++j) {
                            int kl = key_lo + ((t >> 1) << 5) + (quad << 3) + ((t & 1) << 2) + j;
                            if (kl > qrow) { acc[0][t][j] = -INFINITY; acc[1][t][j] = -INFINITY; }
                        }
                }
                // ---- online softmax (per-lane row) + pack into PV B-frags ----
                unsigned pk[2][2][4];
                for (int hh = 0; hh < 2; ++hh) {
                    float mx = m_i[hh];
                    for (int t = 0; t < 4; ++t)
                        for (int j = 0; j < 4; ++j) mx = fmaxf(mx, acc[hh][t][j]);
                    mx = fmaxf(mx, __shfl_xor(mx, 16));
                    mx = fmaxf(mx, __shfl_xor(mx, 32));
                    float al = exp2f(m_i[hh] - mx);
                    m_i[hh] = mx;
                    float rs = 0.f;
                    float p[4][4];
                    for (int t = 0; t < 4; ++t)
                        for (int j = 0; j < 4; ++j) {
                            float e = exp2f(acc[hh][t][j] - mx);
                            p[t][j] = e;
                            rs += e;
                        }
                    rs += __shfl_xor(rs, 16);
                    rs += __shfl_xor(rs, 32);
                    l_i[hh] = al * l_i[hh] + rs;
                    for (int d8 = 0; d8 < 8; ++d8)
                        for (int j = 0; j < 4; ++j) o[hh][d8][j] *= al;
                    for (int grp = 0; grp < 2; ++grp) {
                        pk[hh][grp][0] = pack_bf2(p[2 * grp][0],     p[2 * grp][1]);
                        pk[hh][grp][1] = pack_bf2(p[2 * grp][2],     p[2 * grp][3]);
                        pk[hh][grp][2] = pack_bf2(p[2 * grp + 1][0], p[2 * grp + 1][1]);
                        pk[hh][grp][3] = pack_bf2(p[2 * grp + 1][2], p[2 * grp + 1][3]);
                    }
                }
                // ---- O^T += V^T · P^T ----
                for (int grp = 0; grp < 2; ++grp) {
                    union { unsigned u[4]; bf16x8 v; } pb0, pb1;
                    for (int i = 0; i < 4; ++i) { pb0.u[i] = pk[0][grp][i]; pb1.u[i] = pk[1][grp][i]; }
                    for (int d8 = 0; d8 < 8; ++d8) {
                        int d = d8 * 16 + l16;
                        int slot = (eh * 8 + grp * 4 + quad) ^ (d & 15);
                        bf16x8 vf = *(const bf16x8*)(Vb + d * 128 + slot * 8);
                        o[0][d8] = __builtin_amdgcn_mfma_f32_16x16x32_bf16(vf, pb0.v, o[0][d8], 0, 0, 0);
                        o[1][d8] = __builtin_amdgcn_mfma_f32_16x16x32_bf16(vf, pb1.v, o[1][d8], 0, 0, 0);
                    }
                }
            }
            buf ^= 1;
        }
        // ---- merge eh=1 partials into eh=0, normalize, store ----
        __syncthreads();
        if (eh == 1) {
            for (int hh = 0; hh < 2; ++hh)
                for (int d8 = 0; d8 < 8; ++d8)
                    *(f32x4*)(fsm + rw * 4096 + (hh * 8 + d8) * 256 + lane * 4) = o[hh][d8];
            f32x4 ml; ml.x = m_i[0]; ml.y = l_i[0]; ml.z = m_i[1]; ml.w = l_i[1];
            *(f32x4*)(fsm + 16384 + rw * 256 + lane * 4) = ml;
        }
        __syncthreads();
        if (eh == 0) {
            f32x4 mlb = *(const f32x4*)(fsm + 16384 + rw * 256 + lane * 4);
            float mb[2]; mb[0] = mlb.x; mb[1] = mlb.z;
            float lb[2]; lb[0] = mlb.y; lb[1] = mlb.w;
            for (int hh = 0; hh < 2; ++hh) {
                float m  = fmaxf(m_i[hh], mb[hh]);
                float aA = exp2f(m_i[hh] - m);
                float aB = exp2f(mb[hh] - m);
                float il = 1.0f / (l_i[hh] * aA + lb[hh] * aB);
                float sA = aA * il, sB = aB * il;
                short* op = aout + ((size_t)(b * S_ + qrow) * NH_ + h0 + hh) * HD_ + quad * 4;
                for (int d8 = 0; d8 < 8; ++d8) {
                    f32x4 ob = *(const f32x4*)(fsm + rw * 4096 + (hh * 8 + d8) * 256 + lane * 4);
                    float v0 = o[hh][d8][0] * sA + ob[0] * sB;
                    float v1 = o[hh][d8][1] * sA + ob[1] * sB;
                    float v2 = o[hh][d8][2] * sA + ob[2] * sB;
                    float v3 = o[hh][d8][3] * sA + ob[3] * sB;
                    uint2v wv;
                    wv.x = ((unsigned)(unsigned short)f2bf(v0)) |
                           ((unsigned)(unsigned short)f2bf(v1) << 16);
                    wv.y = ((unsigned)(unsigned short)f2bf(v2)) |
                           ((unsigned)(unsigned short)f2bf(v3) << 16);
                    *(uint2v*)(op + d8 * 16) = wv;
                }
            }
        }
        __syncthreads();   // merge reads done before next pass restages smem
    }
}

// ---------------------------------------------------------------------------
extern "C" void kernel_launch(void* const* d_in, const int* in_sizes, int n_in,
                              void* d_out, int out_size, void* d_ws, size_t ws_size,
                              hipStream_t stream) {
    (void)in_sizes; (void)n_in; (void)out_size; (void)ws_size;
    const float* x    = (const float*)d_in[0];
    const float* cosb = (const float*)d_in[1];
    const float* sinb = (const float*)d_in[2];
    const float* Wq   = (const float*)d_in[3];
    const float* Wk   = (const float*)d_in[4];
    const float* Wv   = (const float*)d_in[5];
    const float* Wo   = (const float*)d_in[6];
    const float* qw   = (const float*)d_in[7];
    const float* kw   = (const float*)d_in[8];
    float* out = (float*)d_out;

    char* ws = (char*)d_ws;
    short* qkv    = (short*)ws;  ws += (size_t)4096 * NQKV_ * 2;   // 24MB bf16
    short* xb     = (short*)ws;  ws += (size_t)4096 * 2048 * 2;    // 16MB
    short* Wt     = (short*)ws;  ws += (size_t)NQKV_ * 2048 * 2;   // 12MB [n][k]
    short* Wot    = (short*)ws;  ws += (size_t)2048 * 2048 * 2;    // 8MB  [n][k]
    short* q_rope = (short*)ws;  ws += (size_t)4096 * 2048 * 2;    // 16MB (b,s,h,hd)
    short* k_rope = (short*)ws;  ws += (size_t)4096 * 512 * 2;     // 4MB  (b,g,s,hd)
    short* vt     = (short*)ws;  ws += (size_t)4096 * 512 * 2;     // 4MB  (b,g,hd,s)
    short* a_out  = (short*)ws;  ws += (size_t)4096 * 2048 * 2;    // 16MB

    const int M = B_ * S_;  // 4096

    // pre-pass: bf16 casts + weight transposes
    cast_kernel<<<M * 2048 / 1024, 256, 0, stream>>>(x, xb);
    transpose_cast_kernel<<<dim3(2048 / 64, 2048 / 64), 256, 0, stream>>>(Wq, Wt, 2048, 2048);
    transpose_cast_kernel<<<dim3(512 / 64, 2048 / 64), 256, 0, stream>>>(Wk, Wt + (size_t)KOFF_ * 2048, 2048, 512);
    transpose_cast_kernel<<<dim3(512 / 64, 2048 / 64), 256, 0, stream>>>(Wv, Wt + (size_t)VOFF_ * 2048, 2048, 512);
    transpose_cast_kernel<<<dim3(2048 / 64, 2048 / 64), 256, 0, stream>>>(Wo, Wot, 2048, 2048);

    // fused QKV projection: [4096][2048] @ [2048][3072] -> bf16 [4096][3072]
    gemm_tt_kernel<short><<<dim3(NQKV_ / 128, M / 128), 256, 0, stream>>>(
        xb, Wt, qkv, M, NQKV_, 2048);

    // RMSNorm + RoPE (Q pre-scaled into exp2 basis); V transpose
    rope_rms_kernel<NH_, false><<<M * NH_ / 4, 256, 0, stream>>>(
        qkv, 0, cosb, sinb, qw, q_rope, SCALE_ * LOG2E_);
    rope_rms_kernel<NKV_, true><<<M * NKV_ / 4, 256, 0, stream>>>(
        qkv, KOFF_, cosb, sinb, kw, k_rope, 1.0f);
    vtrans_kernel<<<dim3(S_ / 64, HD_ / 64, B_ * NKV_), 256, 0, stream>>>(qkv, vt);

    // causal GQA flash attention: 256 equal blocks x 512 threads
    attn_kernel<<<256, 512, 0, stream>>>(q_rope, k_rope, vt, a_out);

    // output projection: [4096][2048] @ [2048][2048] -> fp32 out
    gemm_tt_kernel<float><<<dim3(D_ / 128, M / 128), 256, 0, stream>>>(
        a_out, Wot, out, M, D_, 2048);
}

// Round 6
// 330.254 us; speedup vs baseline: 3.6737x; 1.0206x over previous
//
#include <hip/hip_runtime.h>
#include <hip/hip_bf16.h>
#include <math.h>

#define B_ 2
#define S_ 2048
#define D_ 2048
#define NH_ 16
#define NKV_ 4
#define HD_ 128
#define EPS_ 1e-6f
#define SCALE_ 0.08838834764831845f  // 1/sqrt(128)
#define LOG2E_ 1.4426950408889634f
#define NQKV_ 3072                   // fused QKV output width
#define KOFF_ 2048                   // k slice column offset in fused qkv
#define VOFF_ 2560                   // v slice column offset in fused qkv

typedef float f32x4 __attribute__((ext_vector_type(4)));
typedef short bf16x8 __attribute__((ext_vector_type(8)));
typedef short short4v __attribute__((ext_vector_type(4)));
typedef float float4v __attribute__((ext_vector_type(4)));
typedef unsigned uint2v __attribute__((ext_vector_type(2)));

static __device__ __forceinline__ short f2bf(float f) {
    union { float f; unsigned u; } x{f};
    unsigned r = (x.u + 0x7fff + ((x.u >> 16) & 1)) >> 16;   // RTNE
    return (short)r;
}
static __device__ __forceinline__ float bf2f(short s) {
    union { unsigned u; float f; } x; x.u = ((unsigned)(unsigned short)s) << 16; return x.f;
}
// pack two fp32 -> two bf16 (truncation) in ONE v_perm: lo16=hi16(a), hi16=hi16(b)
static __device__ __forceinline__ unsigned pack_bf2(float a, float b) {
    return __builtin_amdgcn_perm(__builtin_bit_cast(unsigned, b),
                                 __builtin_bit_cast(unsigned, a), 0x07060302u);
}

#define AS1(p) ((const __attribute__((address_space(1))) void*)(p))
#define AS3(p) ((__attribute__((address_space(3))) void*)(p))
static __device__ __forceinline__ void async16(const void* g, void* l) {
    __builtin_amdgcn_global_load_lds(AS1(g), AS3(l), 16, 0, 0);
}

// ---------------------------------------------------------------------------
// fp32 -> bf16 flat cast (for x). 4 elems/thread.
// ---------------------------------------------------------------------------
__global__ __launch_bounds__(256) void cast_kernel(const float* __restrict__ in,
                                                   short* __restrict__ out) {
    size_t i = ((size_t)blockIdx.x * 256 + threadIdx.x) * 4;
    float4v v = *(const float4v*)(in + i);
    short4v o; o.x = f2bf(v.x); o.y = f2bf(v.y); o.z = f2bf(v.z); o.w = f2bf(v.w);
    *(short4v*)(out + i) = o;
}

// ---------------------------------------------------------------------------
// fp32 [K][N] -> bf16 [N][K] transpose+cast. 64x64 tiles, 256 threads.
// Vectorized short4 stores (16 lanes x 8B = 128B contiguous per quarter-wave).
// ---------------------------------------------------------------------------
__global__ __launch_bounds__(256) void transpose_cast_kernel(const float* __restrict__ in,
                                                             short* __restrict__ out,
                                                             int K, int N) {
    __shared__ float tile[64][65];
    const int n0 = blockIdx.x * 64, k0 = blockIdx.y * 64;
    const int tid = threadIdx.x;
    for (int r = 0; r < 16; ++r) {
        int k = r * 4 + (tid >> 6);
        int n = tid & 63;
        tile[k][n] = in[(size_t)(k0 + k) * N + n0 + n];
    }
    __syncthreads();
    for (int r = 0; r < 4; ++r) {
        int n  = r * 16 + (tid >> 4);
        int kk = (tid & 15) * 4;
        short4v o4;
        o4.x = f2bf(tile[kk + 0][n]); o4.y = f2bf(tile[kk + 1][n]);
        o4.z = f2bf(tile[kk + 2][n]); o4.w = f2bf(tile[kk + 3][n]);
        *(short4v*)&out[(size_t)(n0 + n) * K + k0 + kk] = o4;
    }
}

// ---------------------------------------------------------------------------
// m97-style GEMM: C[M][N] = A[M][K] @ Bt[N][K]^T, A/Bt bf16, C fp32 or bf16.
// 128x128 tile, BK=32, global_load_lds width-16, rotation-swizzled LDS chunks.
// ---------------------------------------------------------------------------
template<typename TC>
__global__ __launch_bounds__(256) void gemm_tt_kernel(const short* __restrict__ A,
                                                      const short* __restrict__ Bt,
                                                      TC* __restrict__ C,
                                                      int M, int N, int K) {
    __shared__ short As[128 * 32];   // [row][4 chunks of 8 bf16], chunk c at slot (c + (r>>1))&3
    __shared__ short Bs[128 * 32];

    const int tid  = threadIdx.x;
    const int bn   = blockIdx.x, bm = blockIdx.y;
    const int wave = tid >> 6, lane = tid & 63;
    const int quad = lane >> 4, l16 = lane & 15;
    const int wr = wave >> 1, wc = wave & 1;

    f32x4 acc[4][4];
    for (int i = 0; i < 4; ++i)
        for (int j = 0; j < 4; ++j) acc[i][j] = (f32x4){0.f, 0.f, 0.f, 0.f};

    const short* Abase = A  + (size_t)(bm * 128) * K;
    const short* Bbase = Bt + (size_t)(bn * 128) * K;

    int ci0 = wave * 128 + lane;
    for (int k0 = 0; k0 < K; k0 += 32) {
        __syncthreads();
        for (int t = 0; t < 2; ++t) {
            int ci = ci0 + t * 64;          // 0..511
            int r  = ci >> 2;
            int c  = ((ci & 3) - (r >> 1)) & 3;
            size_t goff = (size_t)r * K + k0 + c * 8;
            async16(Abase + goff, &As[ci * 8]);
            async16(Bbase + goff, &Bs[ci * 8]);
        }
        __syncthreads();

        bf16x8 af[4], bfv[4];
        for (int mt = 0; mt < 4; ++mt) {
            int r = wr * 64 + mt * 16 + l16;
            af[mt] = *(const bf16x8*)&As[r * 32 + (((quad + (r >> 1)) & 3) * 8)];
        }
        for (int nt = 0; nt < 4; ++nt) {
            int r = wc * 64 + nt * 16 + l16;
            bfv[nt] = *(const bf16x8*)&Bs[r * 32 + (((quad + (r >> 1)) & 3) * 8)];
        }
        for (int mt = 0; mt < 4; ++mt)
            for (int nt = 0; nt < 4; ++nt)
                acc[mt][nt] = __builtin_amdgcn_mfma_f32_16x16x32_bf16(
                    af[mt], bfv[nt], acc[mt][nt], 0, 0, 0);
    }

    for (int mt = 0; mt < 4; ++mt)
        for (int nt = 0; nt < 4; ++nt)
            for (int j = 0; j < 4; ++j) {
                int row = bm * 128 + wr * 64 + mt * 16 + quad * 4 + j;
                int col = bn * 128 + wc * 64 + nt * 16 + l16;
                float v = acc[mt][nt][j];
                if constexpr (__is_same(TC, short))
                    C[(size_t)row * N + col] = f2bf(v);
                else
                    C[(size_t)row * N + col] = v;
            }
}

// ---------------------------------------------------------------------------
// RMSNorm + RoPE from bf16 qkv rows. 4 rows per 256-block (1/wave).
// HEAD_MAJOR=false: out (b,s,head,hd); true: out (b,head,s,hd).
// outscale folds attention logit scaling (in exp2 basis) into Q.
// ---------------------------------------------------------------------------
template<int NHEADS, bool HEAD_MAJOR>
__global__ __launch_bounds__(256) void rope_rms_kernel(const short* __restrict__ qkv,
                                                       int coloff,
                                                       const float* __restrict__ cosb,
                                                       const float* __restrict__ sinb,
                                                       const float* __restrict__ w,
                                                       short* __restrict__ out,
                                                       float outscale) {
    const int r    = blockIdx.x * 4 + (threadIdx.x >> 6);  // token*NHEADS + head
    const int lane = threadIdx.x & 63;
    const int tok  = r / NHEADS, head = r % NHEADS;
    const int spos = tok & (S_ - 1);
    const short* row = qkv + (size_t)tok * NQKV_ + coloff + head * HD_;
    float h1 = bf2f(row[lane]), h2 = bf2f(row[lane + 64]);
    float ss = h1 * h1 + h2 * h2;
    for (int off = 1; off < 64; off <<= 1) ss += __shfl_xor(ss, off);
    float rstd = rsqrtf(ss * (1.0f / HD_) + EPS_);
    float n1 = h1 * rstd * w[lane];
    float n2 = h2 * rstd * w[lane + 64];
    float c  = cosb[spos * HD_ + lane];
    float sn = sinb[spos * HD_ + lane];
    size_t o;
    if (HEAD_MAJOR) {
        int b = tok >> 11, s = tok & (S_ - 1);
        o = ((size_t)(b * NHEADS + head) * S_ + s) * HD_;
    } else {
        o = ((size_t)tok * NHEADS + head) * HD_;
    }
    out[o + lane]      = f2bf((n1 * c - n2 * sn) * outscale);
    out[o + lane + 64] = f2bf((n2 * c + n1 * sn) * outscale);
}

// ---------------------------------------------------------------------------
// V slice of qkv (bf16, at column VOFF_) -> bf16 (b,g,d,s). 64x64 LDS tiles.
// grid (S/64, HD/64, B*NKV)
// ---------------------------------------------------------------------------
__global__ __launch_bounds__(256) void vtrans_kernel(const short* __restrict__ qkv,
                                                     short* __restrict__ vt) {
    __shared__ short tile[64][71];
    const int s0 = blockIdx.x * 64, d0 = blockIdx.y * 64;
    const int g = blockIdx.z & 3, b = blockIdx.z >> 2;
    const int tid = threadIdx.x;
    for (int r = 0; r < 16; ++r) {
        int s = r * 4 + (tid >> 6);
        int d = tid & 63;
        tile[s][d] = qkv[(size_t)(b * S_ + s0 + s) * NQKV_ + VOFF_ + g * HD_ + d0 + d];
    }
    __syncthreads();
    for (int r = 0; r < 16; ++r) {
        int d = r * 4 + (tid >> 6);
        int s = tid & 63;
        vt[((size_t)(b * NKV_ + g) * HD_ + d0 + d) * S_ + s0 + s] = tile[s][d];
    }
}

// ---------------------------------------------------------------------------
// Flash causal GQA attention v4: 512 equal blocks x 256 thr (4 waves),
// 64KB LDS -> 2 independent blocks/CU. Block = 1 head x 64 q-rows,
// qt-pair {pr, 31-pr} processed sequentially (33 iters total, all blocks
// identical). 64-key K/V tiles double-buffered; no split-K, no merge.
// K LDS swizzle c ^ ((key^(key>>2))&15) -> 2-way (free) frag-read banks.
// qr pre-scaled by SCALE*log2e. kg (b,g,s,hd); vt (b,g,hd,s); aout (b,s,h,hd).
// ---------------------------------------------------------------------------
__global__ __launch_bounds__(256, 2) void attn_kernel(const short* __restrict__ qr,
                                                      const short* __restrict__ kg,
                                                      const short* __restrict__ vt,
                                                      short* __restrict__ aout) {
    __shared__ short Ks[2][64 * 128];   // 16KB each buf
    __shared__ short Vs[2][128 * 64];   // 16KB each buf

    const int lin = blockIdx.x;          // 512 = 2b x 4g x 4hq x 16pr
    const int b  = lin & 1;
    const int g  = (lin >> 1) & 3;
    const int hq = (lin >> 3) & 3;
    const int pr = lin >> 5;             // 0..15
    const int h  = g * 4 + hq;

    const int wave = threadIdx.x >> 6, lane = threadIdx.x & 63;
    const int quad = lane >> 4, l16 = lane & 15;

    const short* kbase = kg + (size_t)(b * NKV_ + g) * S_ * HD_;
    const short* vbase = vt + (size_t)(b * NKV_ + g) * HD_ * S_;

    for (int pass = 0; pass < 2; ++pass) {
        const int qt    = pass ? (31 - pr) : pr;
        const int iters = qt + 1;
        const int qrow  = qt * 64 + wave * 16 + l16;

        bf16x8 qf[4];
        {
            const short* qp = qr + ((size_t)(b * S_ + qrow) * NH_ + h) * HD_;
            for (int ks = 0; ks < 4; ++ks)
                qf[ks] = *(const bf16x8*)(qp + ks * 32 + quad * 8);
        }

        f32x4 o[8];
        for (int i = 0; i < 8; ++i) o[i] = (f32x4){0.f, 0.f, 0.f, 0.f};
        float m_i = -INFINITY, l_i = 0.f;

        auto stage = [&](int kt, int bsel) {
            const short* kt_base = kbase + (size_t)kt * 64 * HD_;
            const short* vt_base = vbase + kt * 64;
            for (int t = 0; t < 4; ++t) {
                int ci  = (wave * 4 + t) * 64 + lane;   // 0..1023
                int key = ci >> 4;
                int c   = (ci & 15) ^ ((key ^ (key >> 2)) & 15);
                async16(kt_base + key * HD_ + c * 8, &Ks[bsel][ci * 8]);
            }
            for (int t = 0; t < 4; ++t) {
                int ci = (wave * 4 + t) * 64 + lane;    // 0..1023
                int d  = ci >> 3;
                int c  = (ci & 7) ^ (d & 7);
                async16(vt_base + (size_t)d * S_ + c * 8, &Vs[bsel][ci * 8]);
            }
        };

        stage(0, 0);
        int buf = 0;
        for (int kt = 0; kt < iters; ++kt) {
            __syncthreads();                 // tile[buf] staged & visible
            if (kt + 1 < iters) stage(kt + 1, buf ^ 1);

            // ---- S^T = K·Q^T over 64 keys (permuted m-rows) ----
            f32x4 acc[4];
            for (int t = 0; t < 4; ++t) acc[t] = (f32x4){0.f, 0.f, 0.f, 0.f};
            for (int t = 0; t < 4; ++t) {
                int lk = ((t >> 1) << 5) + ((l16 >> 2) << 3) + ((t & 1) << 2) + (l16 & 3);
                const short* kp = &Ks[buf][lk * 128];
                int pm = (lk ^ (lk >> 2)) & 15;
                for (int ks = 0; ks < 4; ++ks) {
                    bf16x8 kf = *(const bf16x8*)(kp + (((ks * 4 + quad) ^ pm) * 8));
                    acc[t] = __builtin_amdgcn_mfma_f32_16x16x32_bf16(kf, qf[ks], acc[t], 0, 0, 0);
                }
            }
            const int key_base = kt * 64;
            if (key_base + 63 > qt * 64 + wave * 16) {   // diagonal region: causal mask
                for (int t = 0; t < 4; ++t)
                    for (int j = 0; j < 4; ++j) {
                        int kl = key_base + ((t >> 1) << 5) + (quad << 3) + ((t & 1) << 2) + j;
                        if (kl > qrow) acc[t][j] = -INFINITY;
                    }
            }
            // ---- online softmax (per-lane row) + pack into PV B-frags ----
            float mx = m_i;
            for (int t = 0; t < 4; ++t)
                for (int j = 0; j < 4; ++j) mx = fmaxf(mx, acc[t][j]);
            mx = fmaxf(mx, __shfl_xor(mx, 16));
            mx = fmaxf(mx, __shfl_xor(mx, 32));
            float al = __builtin_amdgcn_exp2f(m_i - mx);
            m_i = mx;
            float rs = 0.f;
            float p[4][4];
            for (int t = 0; t < 4; ++t)
                for (int j = 0; j < 4; ++j) {
                    float e = __builtin_amdgcn_exp2f(acc[t][j] - mx);
                    p[t][j] = e;
                    rs += e;
                }
            rs += __shfl_xor(rs, 16);
            rs += __shfl_xor(rs, 32);
            l_i = al * l_i + rs;
            for (int d8 = 0; d8 < 8; ++d8)
                for (int j = 0; j < 4; ++j) o[d8][j] *= al;
            unsigned pk[2][4];
            for (int grp = 0; grp < 2; ++grp) {
                pk[grp][0] = pack_bf2(p[2 * grp][0],     p[2 * grp][1]);
                pk[grp][1] = pack_bf2(p[2 * grp][2],     p[2 * grp][3]);
                pk[grp][2] = pack_bf2(p[2 * grp + 1][0], p[2 * grp + 1][1]);
                pk[grp][3] = pack_bf2(p[2 * grp + 1][2], p[2 * grp + 1][3]);
            }
            // ---- O^T += V^T · P^T ----
            for (int grp = 0; grp < 2; ++grp) {
                union { unsigned u[4]; bf16x8 v; } pb;
                for (int i = 0; i < 4; ++i) pb.u[i] = pk[grp][i];
                for (int d8 = 0; d8 < 8; ++d8) {
                    int d = d8 * 16 + l16;
                    bf16x8 vf = *(const bf16x8*)&Vs[buf][d * 64 + (((grp * 4 + quad) ^ (d & 7)) * 8)];
                    o[d8] = __builtin_amdgcn_mfma_f32_16x16x32_bf16(vf, pb.v, o[d8], 0, 0, 0);
                }
            }
            buf ^= 1;
        }
        // ---- normalize + store bf16 (b,s,h,hd): lane writes 8B chunks ----
        float il = 1.0f / l_i;
        short* op = aout + ((size_t)(b * S_ + qrow) * NH_ + h) * HD_ + quad * 4;
        for (int d8 = 0; d8 < 8; ++d8) {
            uint2v wv;
            wv.x = ((unsigned)(unsigned short)f2bf(o[d8][0] * il)) |
                   ((unsigned)(unsigned short)f2bf(o[d8][1] * il) << 16);
            wv.y = ((unsigned)(unsigned short)f2bf(o[d8][2] * il)) |
                   ((unsigned)(unsigned short)f2bf(o[d8][3] * il) << 16);
            *(uint2v*)(op + d8 * 16) = wv;
        }
        __syncthreads();   // LDS reads done before next pass restages
    }
}

// ---------------------------------------------------------------------------
extern "C" void kernel_launch(void* const* d_in, const int* in_sizes, int n_in,
                              void* d_out, int out_size, void* d_ws, size_t ws_size,
                              hipStream_t stream) {
    (void)in_sizes; (void)n_in; (void)out_size; (void)ws_size;
    const float* x    = (const float*)d_in[0];
    const float* cosb = (const float*)d_in[1];
    const float* sinb = (const float*)d_in[2];
    const float* Wq   = (const float*)d_in[3];
    const float* Wk   = (const float*)d_in[4];
    const float* Wv   = (const float*)d_in[5];
    const float* Wo   = (const float*)d_in[6];
    const float* qw   = (const float*)d_in[7];
    const float* kw   = (const float*)d_in[8];
    float* out = (float*)d_out;

    char* ws = (char*)d_ws;
    short* qkv    = (short*)ws;  ws += (size_t)4096 * NQKV_ * 2;   // 24MB bf16
    short* xb     = (short*)ws;  ws += (size_t)4096 * 2048 * 2;    // 16MB
    short* Wt     = (short*)ws;  ws += (size_t)NQKV_ * 2048 * 2;   // 12MB [n][k]
    short* Wot    = (short*)ws;  ws += (size_t)2048 * 2048 * 2;    // 8MB  [n][k]
    short* q_rope = (short*)ws;  ws += (size_t)4096 * 2048 * 2;    // 16MB (b,s,h,hd)
    short* k_rope = (short*)ws;  ws += (size_t)4096 * 512 * 2;     // 4MB  (b,g,s,hd)
    short* vt     = (short*)ws;  ws += (size_t)4096 * 512 * 2;     // 4MB  (b,g,hd,s)
    short* a_out  = (short*)ws;  ws += (size_t)4096 * 2048 * 2;    // 16MB

    const int M = B_ * S_;  // 4096

    // pre-pass: bf16 casts + weight transposes
    cast_kernel<<<M * 2048 / 1024, 256, 0, stream>>>(x, xb);
    transpose_cast_kernel<<<dim3(2048 / 64, 2048 / 64), 256, 0, stream>>>(Wq, Wt, 2048, 2048);
    transpose_cast_kernel<<<dim3(512 / 64, 2048 / 64), 256, 0, stream>>>(Wk, Wt + (size_t)KOFF_ * 2048, 2048, 512);
    transpose_cast_kernel<<<dim3(512 / 64, 2048 / 64), 256, 0, stream>>>(Wv, Wt + (size_t)VOFF_ * 2048, 2048, 512);
    transpose_cast_kernel<<<dim3(2048 / 64, 2048 / 64), 256, 0, stream>>>(Wo, Wot, 2048, 2048);

    // fused QKV projection: [4096][2048] @ [2048][3072] -> bf16 [4096][3072]
    gemm_tt_kernel<short><<<dim3(NQKV_ / 128, M / 128), 256, 0, stream>>>(
        xb, Wt, qkv, M, NQKV_, 2048);

    // RMSNorm + RoPE (Q pre-scaled into exp2 basis); V transpose
    rope_rms_kernel<NH_, false><<<M * NH_ / 4, 256, 0, stream>>>(
        qkv, 0, cosb, sinb, qw, q_rope, SCALE_ * LOG2E_);
    rope_rms_kernel<NKV_, true><<<M * NKV_ / 4, 256, 0, stream>>>(
        qkv, KOFF_, cosb, sinb, kw, k_rope, 1.0f);
    vtrans_kernel<<<dim3(S_ / 64, HD_ / 64, B_ * NKV_), 256, 0, stream>>>(qkv, vt);

    // causal GQA flash attention: 512 equal blocks x 256 threads, 2 blocks/CU
    attn_kernel<<<512, 256, 0, stream>>>(q_rope, k_rope, vt, a_out);

    // output projection: [4096][2048] @ [2048][2048] -> fp32 out
    gemm_tt_kernel<float><<<dim3(D_ / 128, M / 128), 256, 0, stream>>>(
        a_out, Wot, out, M, D_, 2048);
}

// Round 7
// 329.612 us; speedup vs baseline: 3.6809x; 1.0019x over previous
//
#include <hip/hip_runtime.h>
#include <hip/hip_bf16.h>
#include <math.h>

#define B_ 2
#define S_ 2048
#define D_ 2048
#define NH_ 16
#define NKV_ 4
#define HD_ 128
#define EPS_ 1e-6f
#define SCALE_ 0.08838834764831845f  // 1/sqrt(128)
#define LOG2E_ 1.4426950408889634f
#define KOFF_ 2048                   // k rows offset in fused Wt
#define VOFF_ 2560                   // v rows offset in fused Wt

typedef float f32x4 __attribute__((ext_vector_type(4)));
typedef short bf16x8 __attribute__((ext_vector_type(8)));
typedef short short4v __attribute__((ext_vector_type(4)));
typedef float float4v __attribute__((ext_vector_type(4)));
typedef unsigned uint2v __attribute__((ext_vector_type(2)));

static __device__ __forceinline__ short f2bf(float f) {
    union { float f; unsigned u; } x{f};
    unsigned r = (x.u + 0x7fff + ((x.u >> 16) & 1)) >> 16;   // RTNE
    return (short)r;
}
static __device__ __forceinline__ float bf2f(short s) {
    union { unsigned u; float f; } x; x.u = ((unsigned)(unsigned short)s) << 16; return x.f;
}
// pack two fp32 -> two bf16 (truncation) in ONE v_perm: lo16=hi16(a), hi16=hi16(b)
static __device__ __forceinline__ unsigned pack_bf2(float a, float b) {
    return __builtin_amdgcn_perm(__builtin_bit_cast(unsigned, b),
                                 __builtin_bit_cast(unsigned, a), 0x07060302u);
}

#define AS1(p) ((const __attribute__((address_space(1))) void*)(p))
#define AS3(p) ((__attribute__((address_space(3))) void*)(p))
static __device__ __forceinline__ void async16(const void* g, void* l) {
    __builtin_amdgcn_global_load_lds(AS1(g), AS3(l), 16, 0, 0);
}

// ---------------------------------------------------------------------------
// fp32 -> bf16 flat cast (for x). 4 elems/thread.
// ---------------------------------------------------------------------------
__global__ __launch_bounds__(256) void cast_kernel(const float* __restrict__ in,
                                                   short* __restrict__ out) {
    size_t i = ((size_t)blockIdx.x * 256 + threadIdx.x) * 4;
    float4v v = *(const float4v*)(in + i);
    short4v o; o.x = f2bf(v.x); o.y = f2bf(v.y); o.z = f2bf(v.z); o.w = f2bf(v.w);
    *(short4v*)(out + i) = o;
}

// ---------------------------------------------------------------------------
// All 4 weight transposes in ONE launch. fp32 [K=2048][N] -> bf16 [N][2048].
// grid (80, 32): bx<32 Wq | <40 Wk | <48 Wv | else Wo.
// ---------------------------------------------------------------------------
__global__ __launch_bounds__(256) void transpose_all_kernel(const float* __restrict__ Wq,
                                                            const float* __restrict__ Wk,
                                                            const float* __restrict__ Wv,
                                                            const float* __restrict__ Wo,
                                                            short* __restrict__ Wt,
                                                            short* __restrict__ Wot) {
    __shared__ float tile[64][65];
    const int bx = blockIdx.x, by = blockIdx.y;
    const float* src; short* dst; int N, nb;
    if (bx < 32)      { src = Wq; dst = Wt;                         N = 2048; nb = bx; }
    else if (bx < 40) { src = Wk; dst = Wt + (size_t)KOFF_ * 2048;  N = 512;  nb = bx - 32; }
    else if (bx < 48) { src = Wv; dst = Wt + (size_t)VOFF_ * 2048;  N = 512;  nb = bx - 40; }
    else              { src = Wo; dst = Wot;                        N = 2048; nb = bx - 48; }
    const int n0 = nb * 64, k0 = by * 64;
    const int tid = threadIdx.x;
    for (int r = 0; r < 16; ++r) {
        int k = r * 4 + (tid >> 6);
        int n = tid & 63;
        tile[k][n] = src[(size_t)(k0 + k) * N + n0 + n];
    }
    __syncthreads();
    for (int r = 0; r < 4; ++r) {
        int n  = r * 16 + (tid >> 4);
        int kk = (tid & 15) * 4;
        short4v o4;
        o4.x = f2bf(tile[kk + 0][n]); o4.y = f2bf(tile[kk + 1][n]);
        o4.z = f2bf(tile[kk + 2][n]); o4.w = f2bf(tile[kk + 3][n]);
        *(short4v*)&dst[(size_t)(n0 + n) * 2048 + k0 + kk] = o4;
    }
}

// ---------------------------------------------------------------------------
// m97-style GEMM (used for O-proj): C[M][N] = A[M][K] @ Bt[N][K]^T, fp32 out.
// ---------------------------------------------------------------------------
template<typename TC>
__global__ __launch_bounds__(256) void gemm_tt_kernel(const short* __restrict__ A,
                                                      const short* __restrict__ Bt,
                                                      TC* __restrict__ C,
                                                      int M, int N, int K) {
    __shared__ short As[128 * 32];
    __shared__ short Bs[128 * 32];

    const int tid  = threadIdx.x;
    const int bn   = blockIdx.x, bm = blockIdx.y;
    const int wave = tid >> 6, lane = tid & 63;
    const int quad = lane >> 4, l16 = lane & 15;
    const int wr = wave >> 1, wc = wave & 1;

    f32x4 acc[4][4];
    for (int i = 0; i < 4; ++i)
        for (int j = 0; j < 4; ++j) acc[i][j] = (f32x4){0.f, 0.f, 0.f, 0.f};

    const short* Abase = A  + (size_t)(bm * 128) * K;
    const short* Bbase = Bt + (size_t)(bn * 128) * K;

    int ci0 = wave * 128 + lane;
    for (int k0 = 0; k0 < K; k0 += 32) {
        __syncthreads();
        for (int t = 0; t < 2; ++t) {
            int ci = ci0 + t * 64;
            int r  = ci >> 2;
            int c  = ((ci & 3) - (r >> 1)) & 3;
            size_t goff = (size_t)r * K + k0 + c * 8;
            async16(Abase + goff, &As[ci * 8]);
            async16(Bbase + goff, &Bs[ci * 8]);
        }
        __syncthreads();

        bf16x8 af[4], bfv[4];
        for (int mt = 0; mt < 4; ++mt) {
            int r = wr * 64 + mt * 16 + l16;
            af[mt] = *(const bf16x8*)&As[r * 32 + (((quad + (r >> 1)) & 3) * 8)];
        }
        for (int nt = 0; nt < 4; ++nt) {
            int r = wc * 64 + nt * 16 + l16;
            bfv[nt] = *(const bf16x8*)&Bs[r * 32 + (((quad + (r >> 1)) & 3) * 8)];
        }
        for (int mt = 0; mt < 4; ++mt)
            for (int nt = 0; nt < 4; ++nt)
                acc[mt][nt] = __builtin_amdgcn_mfma_f32_16x16x32_bf16(
                    af[mt], bfv[nt], acc[mt][nt], 0, 0, 0);
    }

    for (int mt = 0; mt < 4; ++mt)
        for (int nt = 0; nt < 4; ++nt)
            for (int j = 0; j < 4; ++j) {
                int row = bm * 128 + wr * 64 + mt * 16 + quad * 4 + j;
                int col = bn * 128 + wc * 64 + nt * 16 + l16;
                float v = acc[mt][nt][j];
                if constexpr (__is_same(TC, short))
                    C[(size_t)row * N + col] = f2bf(v);
                else
                    C[(size_t)row * N + col] = v;
            }
}

// ---------------------------------------------------------------------------
// Fused QKV GEMM + RMSNorm + RoPE + V-transpose.
// C = xb[4096][2048] @ Wt[3072][2048]^T, tile 128x128, grid (24, 32).
// bn<16: Q head bn -> q_rope (b,s,h,hd), RMS+RoPE, scaled by SCALE*log2e.
// bn<20: K head bn-16 -> k_rope (b,g,s,hd), RMS+RoPE.
// else : V head bn-20 -> vt (b,g,d,s), raw bf16 (direct 8B token-run stores).
// ---------------------------------------------------------------------------
__global__ __launch_bounds__(256) void qkv_fused_kernel(const short* __restrict__ xb,
                                                        const short* __restrict__ Wt,
                                                        const float* __restrict__ cosb,
                                                        const float* __restrict__ sinb,
                                                        const float* __restrict__ qw,
                                                        const float* __restrict__ kw,
                                                        short* __restrict__ q_rope,
                                                        short* __restrict__ k_rope,
                                                        short* __restrict__ vtr) {
    __shared__ short tile[128 * 128];   // 32KB; first 16KB doubles as As|Bs
    __shared__ float ss2[2][128];
    short* As = tile;
    short* Bs = tile + 4096;

    const int tid  = threadIdx.x;
    const int bn   = blockIdx.x, bm = blockIdx.y;
    const int wave = tid >> 6, lane = tid & 63;
    const int quad = lane >> 4, l16 = lane & 15;
    const int wr = wave >> 1, wc = wave & 1;

    f32x4 acc[4][4];
    for (int i = 0; i < 4; ++i)
        for (int j = 0; j < 4; ++j) acc[i][j] = (f32x4){0.f, 0.f, 0.f, 0.f};

    const short* Abase = xb + (size_t)(bm * 128) * 2048;
    const short* Bbase = Wt + (size_t)(bn * 128) * 2048;

    int ci0 = wave * 128 + lane;
    for (int k0 = 0; k0 < 2048; k0 += 32) {
        __syncthreads();
        for (int t = 0; t < 2; ++t) {
            int ci = ci0 + t * 64;
            int r  = ci >> 2;
            int c  = ((ci & 3) - (r >> 1)) & 3;
            size_t goff = (size_t)r * 2048 + k0 + c * 8;
            async16(Abase + goff, &As[ci * 8]);
            async16(Bbase + goff, &Bs[ci * 8]);
        }
        __syncthreads();

        bf16x8 af[4], bfv[4];
        for (int mt = 0; mt < 4; ++mt) {
            int r = wr * 64 + mt * 16 + l16;
            af[mt] = *(const bf16x8*)&As[r * 32 + (((quad + (r >> 1)) & 3) * 8)];
        }
        for (int nt = 0; nt < 4; ++nt) {
            int r = wc * 64 + nt * 16 + l16;
            bfv[nt] = *(const bf16x8*)&Bs[r * 32 + (((quad + (r >> 1)) & 3) * 8)];
        }
        for (int mt = 0; mt < 4; ++mt)
            for (int nt = 0; nt < 4; ++nt)
                acc[mt][nt] = __builtin_amdgcn_mfma_f32_16x16x32_bf16(
                    af[mt], bfv[nt], acc[mt][nt], 0, 0, 0);
    }

    if (bn >= 20) {
        // ---- V: direct transposed store, (b,g,d,s), 4-token runs of 8B ----
        const int g = bn - 20;
        for (int mt = 0; mt < 4; ++mt) {
            int tok0 = bm * 128 + wr * 64 + mt * 16 + quad * 4;
            int bb = tok0 >> 11, s0 = tok0 & (S_ - 1);
            for (int nt = 0; nt < 4; ++nt) {
                int d = wc * 64 + nt * 16 + l16;
                short4v o4;
                o4.x = f2bf(acc[mt][nt][0]); o4.y = f2bf(acc[mt][nt][1]);
                o4.z = f2bf(acc[mt][nt][2]); o4.w = f2bf(acc[mt][nt][3]);
                *(short4v*)&vtr[((size_t)(bb * NKV_ + g) * HD_ + d) * S_ + s0] = o4;
            }
        }
        return;
    }

    // ---- Q/K: RMSNorm + RoPE ----
    __syncthreads();   // all waves finished reading As/Bs; safe to reuse tile
    // per-row partial sum of squares over this wave's 64 cols (fp32 accs)
    {
        float pss[4][4];
        for (int mt = 0; mt < 4; ++mt)
            for (int j = 0; j < 4; ++j) {
                float s = 0.f;
                for (int nt = 0; nt < 4; ++nt) s += acc[mt][nt][j] * acc[mt][nt][j];
                pss[mt][j] = s;
            }
        for (int off = 1; off < 16; off <<= 1)
            for (int mt = 0; mt < 4; ++mt)
                for (int j = 0; j < 4; ++j)
                    pss[mt][j] += __shfl_xor(pss[mt][j], off);
        if (l16 == 0)
            for (int mt = 0; mt < 4; ++mt)
                for (int j = 0; j < 4; ++j)
                    ss2[wc][wr * 64 + mt * 16 + quad * 4 + j] = pss[mt][j];
    }
    // raw bf16 C into LDS tile [row][col]
    for (int mt = 0; mt < 4; ++mt)
        for (int nt = 0; nt < 4; ++nt)
            for (int j = 0; j < 4; ++j)
                tile[(wr * 64 + mt * 16 + quad * 4 + j) * 128 + wc * 64 + nt * 16 + l16]
                    = f2bf(acc[mt][nt][j]);
    __syncthreads();

    const bool isQ = (bn < 16);
    const float osc = isQ ? (SCALE_ * LOG2E_) : 1.0f;
    const float* w = isQ ? qw : kw;
    for (int it = 0; it < 8; ++it) {
        int idx = tid + it * 256;
        int row = idx >> 4, seg = idx & 15;
        int tok = bm * 128 + row;
        int bb = tok >> 11, s = tok & (S_ - 1);
        float rstd = rsqrtf((ss2[0][row] + ss2[1][row]) * (1.0f / HD_) + EPS_);
        int c0 = seg * 8, p0 = (seg ^ 8) * 8;
        bf16x8 ta = *(const bf16x8*)&tile[row * 128 + c0];
        bf16x8 tb = *(const bf16x8*)&tile[row * 128 + p0];
        float sgn = (seg < 8) ? -1.0f : 1.0f;
        unsigned ov[4];
        for (int i2 = 0; i2 < 4; ++i2) {
            float r0, r1;
            for (int k = 0; k < 2; ++k) {
                int i = i2 * 2 + k;
                float n1 = bf2f(ta[i]) * rstd * w[c0 + i];
                float n2 = bf2f(tb[i]) * rstd * w[p0 + i];
                float cs = cosb[(size_t)s * HD_ + c0 + i];
                float sn = sinb[(size_t)s * HD_ + c0 + i];
                float o = (n1 * cs + sgn * n2 * sn) * osc;
                if (k == 0) r0 = o; else r1 = o;
            }
            ov[i2] = ((unsigned)(unsigned short)f2bf(r0)) |
                     ((unsigned)(unsigned short)f2bf(r1) << 16);
        }
        short* dst = isQ
            ? q_rope + ((size_t)(bb * S_ + s) * NH_ + bn) * HD_ + c0
            : k_rope + ((size_t)(bb * NKV_ + (bn - 16)) * S_ + s) * HD_ + c0;
        uint2v w0; w0.x = ov[0]; w0.y = ov[1];
        uint2v w1; w1.x = ov[2]; w1.y = ov[3];
        *(uint2v*)dst = w0;
        *(uint2v*)(dst + 4) = w1;
    }
}

// ---------------------------------------------------------------------------
// Flash causal GQA attention v4 (unchanged from round 6).
// ---------------------------------------------------------------------------
__global__ __launch_bounds__(256, 2) void attn_kernel(const short* __restrict__ qr,
                                                      const short* __restrict__ kg,
                                                      const short* __restrict__ vt,
                                                      short* __restrict__ aout) {
    __shared__ short Ks[2][64 * 128];
    __shared__ short Vs[2][128 * 64];

    const int lin = blockIdx.x;
    const int b  = lin & 1;
    const int g  = (lin >> 1) & 3;
    const int hq = (lin >> 3) & 3;
    const int pr = lin >> 5;
    const int h  = g * 4 + hq;

    const int wave = threadIdx.x >> 6, lane = threadIdx.x & 63;
    const int quad = lane >> 4, l16 = lane & 15;

    const short* kbase = kg + (size_t)(b * NKV_ + g) * S_ * HD_;
    const short* vbase = vt + (size_t)(b * NKV_ + g) * HD_ * S_;

    for (int pass = 0; pass < 2; ++pass) {
        const int qt    = pass ? (31 - pr) : pr;
        const int iters = qt + 1;
        const int qrow  = qt * 64 + wave * 16 + l16;

        bf16x8 qf[4];
        {
            const short* qp = qr + ((size_t)(b * S_ + qrow) * NH_ + h) * HD_;
            for (int ks = 0; ks < 4; ++ks)
                qf[ks] = *(const bf16x8*)(qp + ks * 32 + quad * 8);
        }

        f32x4 o[8];
        for (int i = 0; i < 8; ++i) o[i] = (f32x4){0.f, 0.f, 0.f, 0.f};
        float m_i = -INFINITY, l_i = 0.f;

        auto stage = [&](int kt, int bsel) {
            const short* kt_base = kbase + (size_t)kt * 64 * HD_;
            const short* vt_base = vbase + kt * 64;
            for (int t = 0; t < 4; ++t) {
                int ci  = (wave * 4 + t) * 64 + lane;
                int key = ci >> 4;
                int c   = (ci & 15) ^ ((key ^ (key >> 2)) & 15);
                async16(kt_base + key * HD_ + c * 8, &Ks[bsel][ci * 8]);
            }
            for (int t = 0; t < 4; ++t) {
                int ci = (wave * 4 + t) * 64 + lane;
                int d  = ci >> 3;
                int c  = (ci & 7) ^ (d & 7);
                async16(vt_base + (size_t)d * S_ + c * 8, &Vs[bsel][ci * 8]);
            }
        };

        stage(0, 0);
        int buf = 0;
        for (int kt = 0; kt < iters; ++kt) {
            __syncthreads();
            if (kt + 1 < iters) stage(kt + 1, buf ^ 1);

            f32x4 acc[4];
            for (int t = 0; t < 4; ++t) acc[t] = (f32x4){0.f, 0.f, 0.f, 0.f};
            for (int t = 0; t < 4; ++t) {
                int lk = ((t >> 1) << 5) + ((l16 >> 2) << 3) + ((t & 1) << 2) + (l16 & 3);
                const short* kp = &Ks[buf][lk * 128];
                int pm = (lk ^ (lk >> 2)) & 15;
                for (int ks = 0; ks < 4; ++ks) {
                    bf16x8 kf = *(const bf16x8*)(kp + (((ks * 4 + quad) ^ pm) * 8));
                    acc[t] = __builtin_amdgcn_mfma_f32_16x16x32_bf16(kf, qf[ks], acc[t], 0, 0, 0);
                }
            }
            const int key_base = kt * 64;
            if (key_base + 63 > qt * 64 + wave * 16) {
                for (int t = 0; t < 4; ++t)
                    for (int j = 0; j < 4; ++j) {
                        int kl = key_base + ((t >> 1) << 5) + (quad << 3) + ((t & 1) << 2) + j;
                        if (kl > qrow) acc[t][j] = -INFINITY;
                    }
            }
            float mx = m_i;
            for (int t = 0; t < 4; ++t)
                for (int j = 0; j < 4; ++j) mx = fmaxf(mx, acc[t][j]);
            mx = fmaxf(mx, __shfl_xor(mx, 16));
            mx = fmaxf(mx, __shfl_xor(mx, 32));
            float al = __builtin_amdgcn_exp2f(m_i - mx);
            m_i = mx;
            float rs = 0.f;
            float p[4][4];
            for (int t = 0; t < 4; ++t)
                for (int j = 0; j < 4; ++j) {
                    float e = __builtin_amdgcn_exp2f(acc[t][j] - mx);
                    p[t][j] = e;
                    rs += e;
                }
            rs += __shfl_xor(rs, 16);
            rs += __shfl_xor(rs, 32);
            l_i = al * l_i + rs;
            for (int d8 = 0; d8 < 8; ++d8)
                for (int j = 0; j < 4; ++j) o[d8][j] *= al;
            unsigned pk[2][4];
            for (int grp = 0; grp < 2; ++grp) {
                pk[grp][0] = pack_bf2(p[2 * grp][0],     p[2 * grp][1]);
                pk[grp][1] = pack_bf2(p[2 * grp][2],     p[2 * grp][3]);
                pk[grp][2] = pack_bf2(p[2 * grp + 1][0], p[2 * grp + 1][1]);
                pk[grp][3] = pack_bf2(p[2 * grp + 1][2], p[2 * grp + 1][3]);
            }
            for (int grp = 0; grp < 2; ++grp) {
                union { unsigned u[4]; bf16x8 v; } pb;
                for (int i = 0; i < 4; ++i) pb.u[i] = pk[grp][i];
                for (int d8 = 0; d8 < 8; ++d8) {
                    int d = d8 * 16 + l16;
                    bf16x8 vf = *(const bf16x8*)&Vs[buf][d * 64 + (((grp * 4 + quad) ^ (d & 7)) * 8)];
                    o[d8] = __builtin_amdgcn_mfma_f32_16x16x32_bf16(vf, pb.v, o[d8], 0, 0, 0);
                }
            }
            buf ^= 1;
        }
        float il = 1.0f / l_i;
        short* op = aout + ((size_t)(b * S_ + qrow) * NH_ + h) * HD_ + quad * 4;
        for (int d8 = 0; d8 < 8; ++d8) {
            uint2v wv;
            wv.x = ((unsigned)(unsigned short)f2bf(o[d8][0] * il)) |
                   ((unsigned)(unsigned short)f2bf(o[d8][1] * il) << 16);
            wv.y = ((unsigned)(unsigned short)f2bf(o[d8][2] * il)) |
                   ((unsigned)(unsigned short)f2bf(o[d8][3] * il) << 16);
            *(uint2v*)(op + d8 * 16) = wv;
        }
        __syncthreads();
    }
}

// ---------------------------------------------------------------------------
extern "C" void kernel_launch(void* const* d_in, const int* in_sizes, int n_in,
                              void* d_out, int out_size, void* d_ws, size_t ws_size,
                              hipStream_t stream) {
    (void)in_sizes; (void)n_in; (void)out_size; (void)ws_size;
    const float* x    = (const float*)d_in[0];
    const float* cosb = (const float*)d_in[1];
    const float* sinb = (const float*)d_in[2];
    const float* Wq   = (const float*)d_in[3];
    const float* Wk   = (const float*)d_in[4];
    const float* Wv   = (const float*)d_in[5];
    const float* Wo   = (const float*)d_in[6];
    const float* qw   = (const float*)d_in[7];
    const float* kw   = (const float*)d_in[8];
    float* out = (float*)d_out;

    char* ws = (char*)d_ws;
    short* xb     = (short*)ws;  ws += (size_t)4096 * 2048 * 2;    // 16MB
    short* Wt     = (short*)ws;  ws += (size_t)3072 * 2048 * 2;    // 12MB [n][k]
    short* Wot    = (short*)ws;  ws += (size_t)2048 * 2048 * 2;    // 8MB  [n][k]
    short* q_rope = (short*)ws;  ws += (size_t)4096 * 2048 * 2;    // 16MB (b,s,h,hd)
    short* k_rope = (short*)ws;  ws += (size_t)4096 * 512 * 2;     // 4MB  (b,g,s,hd)
    short* vt     = (short*)ws;  ws += (size_t)4096 * 512 * 2;     // 4MB  (b,g,hd,s)
    short* a_out  = (short*)ws;  ws += (size_t)4096 * 2048 * 2;    // 16MB

    const int M = B_ * S_;  // 4096

    // pre-pass: x cast + all weight transposes (1 launch)
    cast_kernel<<<M * 2048 / 1024, 256, 0, stream>>>(x, xb);
    transpose_all_kernel<<<dim3(80, 32), 256, 0, stream>>>(Wq, Wk, Wv, Wo, Wt, Wot);

    // fused QKV projection + RMSNorm + RoPE + V transpose
    qkv_fused_kernel<<<dim3(24, M / 128), 256, 0, stream>>>(
        xb, Wt, cosb, sinb, qw, kw, q_rope, k_rope, vt);

    // causal GQA flash attention: 512 equal blocks x 256 threads, 2 blocks/CU
    attn_kernel<<<512, 256, 0, stream>>>(q_rope, k_rope, vt, a_out);

    // output projection: [4096][2048] @ [2048][2048] -> fp32 out
    gemm_tt_kernel<float><<<dim3(D_ / 128, M / 128), 256, 0, stream>>>(
        a_out, Wot, out, M, D_, 2048);
}